// Round 1
// baseline (1680.499 us; speedup 1.0000x reference)
//
#include <hip/hip_runtime.h>
#include <cstdint>

#define NHEAD 12
#define TLEN 2048
#define CDIM 768
#define NSETS 1023   // 512+256+128+64+32+16+8+4+2+1

__device__ __forceinline__ float elu1(float x) { return x > 0.f ? x + 1.f : __expf(x); }

// ---------- generic 64x64-tile f32 GEMM: C = A[M,K] @ B[K,N] (+bias) (+elu+1) ----------
template<int ACT, int BIAS>
__global__ __launch_bounds__(256) void gemm64(
    const float* __restrict__ A, const float* __restrict__ B,
    const float* __restrict__ bias, float* __restrict__ Cmat,
    int M, int N, int K)
{
    __shared__ float As[64][17];
    __shared__ float Bs[16][65];
    const int tid = threadIdx.x;
    const int tx = tid & 15, ty = tid >> 4;
    const int m0 = blockIdx.y * 64, n0 = blockIdx.x * 64;
    float acc[4][4] = {};
    for (int k0 = 0; k0 < K; k0 += 16) {
        #pragma unroll
        for (int i = 0; i < 4; ++i) {
            int e = tid + i * 256;
            int ar = e >> 4, ac = e & 15;
            As[ar][ac] = A[(size_t)(m0 + ar) * K + k0 + ac];
            int br = e >> 6, bc = e & 63;
            Bs[br][bc] = B[(size_t)(k0 + br) * N + n0 + bc];
        }
        __syncthreads();
        #pragma unroll
        for (int kk = 0; kk < 16; ++kk) {
            float ra[4], rb[4];
            #pragma unroll
            for (int a = 0; a < 4; ++a) ra[a] = As[ty + a * 16][kk];
            #pragma unroll
            for (int b = 0; b < 4; ++b) rb[b] = Bs[kk][tx + b * 16];
            #pragma unroll
            for (int a = 0; a < 4; ++a)
                #pragma unroll
                for (int b = 0; b < 4; ++b)
                    acc[a][b] += ra[a] * rb[b];
        }
        __syncthreads();
    }
    #pragma unroll
    for (int a = 0; a < 4; ++a) {
        int m = m0 + ty + a * 16;
        #pragma unroll
        for (int b = 0; b < 4; ++b) {
            int n = n0 + tx + b * 16;
            float v = acc[a][b];
            if (BIAS) v += bias[n];
            if (ACT) v = elu1(v);
            Cmat[(size_t)m * N + n] = v;
        }
    }
}

// ---------- per-position mapped features: kkv[p,d] = sum_{i,j} k[p,i] v[p,j] Wks[i*64+j, d]
// (and vvv with Wvs). A-rows (the 4096-dim kv vectors) are generated on the fly.
// One block = 64 positions (p = t*NHEAD+h flat), all 64 output dims, both maps.
__global__ __launch_bounds__(256) void map_kv(
    const float* __restrict__ kbuf, const float* __restrict__ vbuf,
    const float* __restrict__ Wks, const float* __restrict__ Wvs,
    float* __restrict__ kkv, float* __restrict__ vvv)
{
    __shared__ float kS[64][65];
    __shared__ float vS[64][65];
    __shared__ __align__(16) float wkS[64][64];
    __shared__ __align__(16) float wvS[64][64];
    const int tid = threadIdx.x;
    const int tx = tid & 15, ty = tid >> 4;
    const int p0 = blockIdx.x * 64;

    for (int e = tid; e < 4096; e += 256) {
        int pl = e >> 6, i = e & 63;
        kS[pl][i] = kbuf[(size_t)(p0 + pl) * 64 + i];
        vS[pl][i] = vbuf[(size_t)(p0 + pl) * 64 + i];
    }

    float acck[4][4] = {};
    float accv[4][4] = {};

    for (int i = 0; i < 64; ++i) {
        __syncthreads();   // also guards the kS/vS staging on iter 0
        for (int e = tid; e < 4096; e += 256) {
            wkS[e >> 6][e & 63] = Wks[(size_t)i * 4096 + e];
            wvS[e >> 6][e & 63] = Wvs[(size_t)i * 4096 + e];
        }
        __syncthreads();
        float rk[4];
        #pragma unroll
        for (int a = 0; a < 4; ++a) rk[a] = kS[ty + a * 16][i];
        #pragma unroll 4
        for (int jj = 0; jj < 64; ++jj) {
            float4 wk4 = *(const float4*)&wkS[jj][tx * 4];
            float4 wv4 = *(const float4*)&wvS[jj][tx * 4];
            #pragma unroll
            for (int a = 0; a < 4; ++a) {
                float av = rk[a] * vS[ty + a * 16][jj];
                acck[a][0] += av * wk4.x; acck[a][1] += av * wk4.y;
                acck[a][2] += av * wk4.z; acck[a][3] += av * wk4.w;
                accv[a][0] += av * wv4.x; accv[a][1] += av * wv4.y;
                accv[a][2] += av * wv4.z; accv[a][3] += av * wv4.w;
            }
        }
    }
    #pragma unroll
    for (int a = 0; a < 4; ++a) {
        int p = p0 + ty + a * 16;
        float4 ok = make_float4(acck[a][0], acck[a][1], acck[a][2], acck[a][3]);
        float4 ov = make_float4(accv[a][0], accv[a][1], accv[a][2], accv[a][3]);
        *(float4*)&kkv[(size_t)p * 64 + tx * 4] = ok;
        *(float4*)&vvv[(size_t)p * 64 + tx * 4] = ov;
    }
}

// ---------- tail features: K_tail[t,h,d] = bks[d] + sum_{t'=t&~3}^{t} kkv[t',h,d]
__global__ __launch_bounds__(256) void tail_kernel(
    const float* __restrict__ kkv, const float* __restrict__ vvv,
    const float* __restrict__ bks, const float* __restrict__ bvs,
    float* __restrict__ Kt, float* __restrict__ Vt)
{
    const int idx = blockIdx.x * 256 + threadIdx.x;   // over TLEN*CDIM
    const int t = idx / CDIM;
    const int r = idx % CDIM;
    const int d = r & 63;
    const int t0 = t & ~3;
    float ak = bks[d], av = bvs[d];
    for (int tt = t0; tt <= t; ++tt) {
        ak += kkv[(size_t)tt * CDIM + r];
        av += vvv[(size_t)tt * CDIM + r];
    }
    Kt[idx] = ak;
    Vt[idx] = av;
}

// ---------- set features: K_set[s,h,d] = bks[d] + sum over the dyadic block of kkv
__global__ __launch_bounds__(64) void set_kernel(
    const float* __restrict__ kkv, const float* __restrict__ vvv,
    const float* __restrict__ bks, const float* __restrict__ bvs,
    float* __restrict__ Kset, float* __restrict__ Vset)
{
    const int s = blockIdx.x / NHEAD;
    const int h = blockIdx.x % NHEAD;
    const int d = threadIdx.x;   // 64
    int l = 2, n = 512, rem = s;
    while (rem >= n) { rem -= n; n >>= 1; ++l; }
    const int t0 = rem << l;
    const int len = 1 << l;
    float ak = bks[d], av = bvs[d];
    const float* pk = kkv + (size_t)t0 * CDIM + h * 64 + d;
    const float* pv = vvv + (size_t)t0 * CDIM + h * 64 + d;
    for (int i = 0; i < len; ++i) {
        ak += pk[(size_t)i * CDIM];
        av += pv[(size_t)i * CDIM];
    }
    const size_t o = ((size_t)s * NHEAD + h) * 64 + d;
    Kset[o] = ak;
    Vset[o] = av;
}

// ---------- attention: one block per (t,h); softmax over 1023 sets + tail
__global__ __launch_bounds__(256) void attn_kernel(
    const float* __restrict__ qbuf, const float* __restrict__ Kset,
    const float* __restrict__ Vset, const float* __restrict__ Kt,
    const float* __restrict__ Vt, float* __restrict__ attout)
{
    __shared__ __align__(16) float qs[64];
    __shared__ float lg[1024];      // [0..1022]=sets, [1023]=tail
    __shared__ float red[256];
    const int tid = threadIdx.x;
    const int bid = blockIdx.x;
    const int t = bid / NHEAD, h = bid % NHEAD;
    const int tp1 = t + 1;
    const size_t thbase = ((size_t)t * NHEAD + h) * 64;

    if (tid < 64) qs[tid] = qbuf[thbase + tid];
    __syncthreads();

    // set logits (masked)
    for (int s = tid; s < NSETS; s += 256) {
        int l = 2, n = 512, rem = s;
        while (rem >= n) { rem -= n; n >>= 1; ++l; }
        float val = -1e30f;
        if (rem < (tp1 >> l)) {
            const float4* Kr = (const float4*)(Kset + ((size_t)s * NHEAD + h) * 64);
            const float4* q4 = (const float4*)qs;
            float dot = 0.f;
            #pragma unroll
            for (int i = 0; i < 16; ++i) {
                float4 a = Kr[i], b = q4[i];
                dot += a.x * b.x + a.y * b.y + a.z * b.z + a.w * b.w;
            }
            val = dot * 0.125f;
        }
        lg[s] = val;
    }
    // tail logit
    if (tid < 64) red[tid] = qs[tid] * Kt[thbase + tid];
    __syncthreads();
    if (tid == 0) {
        float sum = 0.f;
        for (int d2 = 0; d2 < 64; ++d2) sum += red[d2];
        lg[1023] = sum * 0.125f;
    }
    __syncthreads();

    // softmax: max
    float m = -1e30f;
    for (int s = tid; s < 1024; s += 256) m = fmaxf(m, lg[s]);
    red[tid] = m;
    __syncthreads();
    for (int off = 128; off > 0; off >>= 1) {
        if (tid < off) red[tid] = fmaxf(red[tid], red[tid + off]);
        __syncthreads();
    }
    const float mx = red[0];
    __syncthreads();
    // softmax: exp + sum
    float sm = 0.f;
    for (int s = tid; s < 1024; s += 256) {
        float e = __expf(lg[s] - mx);
        lg[s] = e;
        sm += e;
    }
    red[tid] = sm;
    __syncthreads();
    for (int off = 128; off > 0; off >>= 1) {
        if (tid < off) red[tid] += red[tid + off];
        __syncthreads();
    }
    const float inv_denom = 1.f / red[0];
    __syncthreads();

    // weighted V accumulation (skip invalid sets by level counts)
    const int g = tid >> 6, d = tid & 63;
    const int LOFF[10] = {0, 512, 768, 896, 960, 992, 1008, 1016, 1020, 1022};
    float acc = 0.f;
    #pragma unroll
    for (int li = 0; li < 10; ++li) {
        int cnt = tp1 >> (li + 2);
        int base = LOFF[li];
        for (int b = g; b < cnt; b += 4)
            acc += lg[base + b] * Vset[((size_t)(base + b) * NHEAD + h) * 64 + d];
    }
    if (g == 0) acc += lg[1023] * Vt[thbase + d];
    red[tid] = acc;
    __syncthreads();
    if (tid < 64) {
        float tot = red[tid] + red[tid + 64] + red[tid + 128] + red[tid + 192];
        attout[thbase + tid] = tot * inv_denom;
    }
}

extern "C" void kernel_launch(void* const* d_in, const int* in_sizes, int n_in,
                              void* d_out, int out_size, void* d_ws, size_t ws_size,
                              hipStream_t stream)
{
    const float* x   = (const float*)d_in[0];
    const float* Wq  = (const float*)d_in[1];
    const float* Wk  = (const float*)d_in[2];
    const float* Wv  = (const float*)d_in[3];
    const float* Wks = (const float*)d_in[4];
    const float* bks = (const float*)d_in[5];
    const float* Wvs = (const float*)d_in[6];
    const float* bvs = (const float*)d_in[7];
    const float* Wc  = (const float*)d_in[8];
    const float* bc  = (const float*)d_in[9];
    float* out = (float*)d_out;

    float* ws = (float*)d_ws;
    const size_t TC = (size_t)TLEN * CDIM;
    float* q      = ws;
    float* k      = q + TC;
    float* v      = k + TC;
    float* kkv    = v + TC;
    float* vvv    = kkv + TC;
    float* Kt     = vvv + TC;
    float* Vt     = Kt + TC;
    float* Kset   = Vt + TC;
    float* Vset   = Kset + (size_t)NSETS * CDIM;
    float* attout = Vset + (size_t)NSETS * CDIM;

    dim3 gg(CDIM / 64, TLEN / 64);  // (12, 32)
    gemm64<1, 0><<<gg, 256, 0, stream>>>(x, Wq, nullptr, q, TLEN, CDIM, CDIM);
    gemm64<1, 0><<<gg, 256, 0, stream>>>(x, Wk, nullptr, k, TLEN, CDIM, CDIM);
    gemm64<0, 0><<<gg, 256, 0, stream>>>(x, Wv, nullptr, v, TLEN, CDIM, CDIM);

    map_kv<<<(TLEN * NHEAD) / 64, 256, 0, stream>>>(k, v, Wks, Wvs, kkv, vvv);

    tail_kernel<<<(TLEN * CDIM) / 256, 256, 0, stream>>>(kkv, vvv, bks, bvs, Kt, Vt);
    set_kernel<<<NSETS * NHEAD, 64, 0, stream>>>(kkv, vvv, bks, bvs, Kset, Vset);

    attn_kernel<<<TLEN * NHEAD, 256, 0, stream>>>(q, Kset, Vset, Kt, Vt, attout);

    gemm64<0, 1><<<gg, 256, 0, stream>>>(attout, Wc, bc, out, TLEN, CDIM, CDIM);
}

// Round 2
// 1172.158 us; speedup vs baseline: 1.4337x; 1.4337x over previous
//
#include <hip/hip_runtime.h>
#include <cstdint>

#define NHEAD 12
#define TLEN 2048
#define CDIM 768
#define NSETS 1023   // 512+256+128+64+32+16+8+4+2+1

__device__ __forceinline__ float elu1(float x) { return x > 0.f ? x + 1.f : __expf(x); }

// ---------- generic 64x64-tile f32 GEMM: C = A[M,K] @ B[K,N] (+bias) (+elu+1) ----------
template<int ACT, int BIAS>
__global__ __launch_bounds__(256) void gemm64(
    const float* __restrict__ A, const float* __restrict__ B,
    const float* __restrict__ bias, float* __restrict__ Cmat,
    int M, int N, int K)
{
    __shared__ float As[64][17];
    __shared__ float Bs[16][65];
    const int tid = threadIdx.x;
    const int tx = tid & 15, ty = tid >> 4;
    const int m0 = blockIdx.y * 64, n0 = blockIdx.x * 64;
    float acc[4][4] = {};
    for (int k0 = 0; k0 < K; k0 += 16) {
        #pragma unroll
        for (int i = 0; i < 4; ++i) {
            int e = tid + i * 256;
            int ar = e >> 4, ac = e & 15;
            As[ar][ac] = A[(size_t)(m0 + ar) * K + k0 + ac];
            int br = e >> 6, bc = e & 63;
            Bs[br][bc] = B[(size_t)(k0 + br) * N + n0 + bc];
        }
        __syncthreads();
        #pragma unroll
        for (int kk = 0; kk < 16; ++kk) {
            float ra[4], rb[4];
            #pragma unroll
            for (int a = 0; a < 4; ++a) ra[a] = As[ty + a * 16][kk];
            #pragma unroll
            for (int b = 0; b < 4; ++b) rb[b] = Bs[kk][tx + b * 16];
            #pragma unroll
            for (int a = 0; a < 4; ++a)
                #pragma unroll
                for (int b = 0; b < 4; ++b)
                    acc[a][b] += ra[a] * rb[b];
        }
        __syncthreads();
    }
    #pragma unroll
    for (int a = 0; a < 4; ++a) {
        int m = m0 + ty + a * 16;
        #pragma unroll
        for (int b = 0; b < 4; ++b) {
            int n = n0 + tx + b * 16;
            float v = acc[a][b];
            if (BIAS) v += bias[n];
            if (ACT) v = elu1(v);
            Cmat[(size_t)m * N + n] = v;
        }
    }
}

// ---------- per-position mapped features ----------
__global__ __launch_bounds__(256) void map_kv(
    const float* __restrict__ kbuf, const float* __restrict__ vbuf,
    const float* __restrict__ Wks, const float* __restrict__ Wvs,
    float* __restrict__ kkv, float* __restrict__ vvv)
{
    __shared__ float kS[64][65];
    __shared__ float vS[64][65];
    __shared__ __align__(16) float wkS[64][64];
    __shared__ __align__(16) float wvS[64][64];
    const int tid = threadIdx.x;
    const int tx = tid & 15, ty = tid >> 4;
    const int p0 = blockIdx.x * 64;

    for (int e = tid; e < 4096; e += 256) {
        int pl = e >> 6, i = e & 63;
        kS[pl][i] = kbuf[(size_t)(p0 + pl) * 64 + i];
        vS[pl][i] = vbuf[(size_t)(p0 + pl) * 64 + i];
    }

    float acck[4][4] = {};
    float accv[4][4] = {};

    for (int i = 0; i < 64; ++i) {
        __syncthreads();
        for (int e = tid; e < 4096; e += 256) {
            wkS[e >> 6][e & 63] = Wks[(size_t)i * 4096 + e];
            wvS[e >> 6][e & 63] = Wvs[(size_t)i * 4096 + e];
        }
        __syncthreads();
        float rk[4];
        #pragma unroll
        for (int a = 0; a < 4; ++a) rk[a] = kS[ty + a * 16][i];
        #pragma unroll 4
        for (int jj = 0; jj < 64; ++jj) {
            float4 wk4 = *(const float4*)&wkS[jj][tx * 4];
            float4 wv4 = *(const float4*)&wvS[jj][tx * 4];
            #pragma unroll
            for (int a = 0; a < 4; ++a) {
                float av = rk[a] * vS[ty + a * 16][jj];
                acck[a][0] += av * wk4.x; acck[a][1] += av * wk4.y;
                acck[a][2] += av * wk4.z; acck[a][3] += av * wk4.w;
                accv[a][0] += av * wv4.x; accv[a][1] += av * wv4.y;
                accv[a][2] += av * wv4.z; accv[a][3] += av * wv4.w;
            }
        }
    }
    #pragma unroll
    for (int a = 0; a < 4; ++a) {
        int p = p0 + ty + a * 16;
        float4 ok = make_float4(acck[a][0], acck[a][1], acck[a][2], acck[a][3]);
        float4 ov = make_float4(accv[a][0], accv[a][1], accv[a][2], accv[a][3]);
        *(float4*)&kkv[(size_t)p * 64 + tx * 4] = ok;
        *(float4*)&vvv[(size_t)p * 64 + tx * 4] = ov;
    }
}

// ---------- tail features ----------
__global__ __launch_bounds__(256) void tail_kernel(
    const float* __restrict__ kkv, const float* __restrict__ vvv,
    const float* __restrict__ bks, const float* __restrict__ bvs,
    float* __restrict__ Kt, float* __restrict__ Vt)
{
    const int idx = blockIdx.x * 256 + threadIdx.x;
    const int t = idx / CDIM;
    const int r = idx % CDIM;
    const int d = r & 63;
    const int t0 = t & ~3;
    float ak = bks[d], av = bvs[d];
    for (int tt = t0; tt <= t; ++tt) {
        ak += kkv[(size_t)tt * CDIM + r];
        av += vvv[(size_t)tt * CDIM + r];
    }
    Kt[idx] = ak;
    Vt[idx] = av;
}

// ---------- set features ----------
__global__ __launch_bounds__(64) void set_kernel(
    const float* __restrict__ kkv, const float* __restrict__ vvv,
    const float* __restrict__ bks, const float* __restrict__ bvs,
    float* __restrict__ Kset, float* __restrict__ Vset)
{
    const int s = blockIdx.x / NHEAD;
    const int h = blockIdx.x % NHEAD;
    const int d = threadIdx.x;
    int l = 2, n = 512, rem = s;
    while (rem >= n) { rem -= n; n >>= 1; ++l; }
    const int t0 = rem << l;
    const int len = 1 << l;
    float ak = bks[d], av = bvs[d];
    const float* pk = kkv + (size_t)t0 * CDIM + h * 64 + d;
    const float* pv = vvv + (size_t)t0 * CDIM + h * 64 + d;
    for (int i = 0; i < len; ++i) {
        ak += pk[(size_t)i * CDIM];
        av += pv[(size_t)i * CDIM];
    }
    const size_t o = ((size_t)s * NHEAD + h) * 64 + d;
    Kset[o] = ak;
    Vset[o] = av;
}

// ---------- tiled flash-style attention ----------
// block = 64 queries x 1 head; iterate 64-set tiles with online softmax.
__global__ __launch_bounds__(256) void attn_tiled(
    const float* __restrict__ qbuf, const float* __restrict__ Kset,
    const float* __restrict__ Vset, const float* __restrict__ Ktail,
    const float* __restrict__ Vtail, float* __restrict__ attout)
{
    __shared__ float qS[64][68];
    __shared__ float kS[64][68];
    __shared__ float vS[64][68];
    __shared__ float sS[64][68];
    __shared__ float mrow[64], lrow[64], arow[64];
    __shared__ float red[64][4];
    __shared__ int   sid[64];
    __shared__ int   send[64];

    const int tid = threadIdx.x;
    const int b   = blockIdx.x / NHEAD;   // t-tile, ascending: heavy blocks dispatched last
    const int h   = blockIdx.x % NHEAD;
    const int T0  = b * 64;
    const int tx  = tid & 15, ty = tid >> 4;

    // per-level valid counts at tile end
    const int Tend = T0 + 64;
    const int LOFF[10] = {0, 512, 768, 896, 960, 992, 1008, 1016, 1020, 1022};
    int cnt[10], pfx[10], Vtot = 0;
    #pragma unroll
    for (int li = 0; li < 10; ++li) { cnt[li] = Tend >> (li + 2); pfx[li] = Vtot; Vtot += cnt[li]; }

    // stage q tile [q][d]
    #pragma unroll
    for (int i = 0; i < 4; ++i) {
        int qi = (tid >> 4) + 16 * i;
        int d4 = tid & 15;
        *(float4*)&qS[qi][d4 * 4] =
            *(const float4*)&qbuf[((size_t)(T0 + qi) * NHEAD + h) * 64 + d4 * 4];
    }
    if (tid < 64) { mrow[tid] = -1e30f; lrow[tid] = 0.f; }

    float acc[4][4] = {};
    const int ntiles = (Vtot + 63) >> 6;

    for (int tile = 0; tile < ntiles; ++tile) {
        __syncthreads();   // protect kS/vS/sS/sid from previous-tile readers (covers qS/mrow init on tile 0)

        // decode 64 set slots
        if (tid < 64) {
            int j = tile * 64 + tid;
            int s_ = 0, e_ = 0x7fffffff;
            if (j < Vtot) {
                int li = 0;
                #pragma unroll
                for (int u = 1; u < 10; ++u) if (j >= pfx[u]) li = u;
                int idx = j - pfx[li];
                s_ = LOFF[li] + idx;
                e_ = (idx + 1) << (li + 2);
            }
            sid[tid] = s_; send[tid] = e_;
        }
        __syncthreads();

        // load K,V tiles [s][d]
        #pragma unroll
        for (int i = 0; i < 4; ++i) {
            int s  = (tid >> 4) + 16 * i;
            int d4 = tid & 15;
            size_t base = ((size_t)sid[s] * NHEAD + h) * 64 + d4 * 4;
            *(float4*)&kS[s][d4 * 4] = *(const float4*)&Kset[base];
            *(float4*)&vS[s][d4 * 4] = *(const float4*)&Vset[base];
        }
        __syncthreads();

        // logits 64x64, thread computes 4x4
        float lacc[4][4] = {};
        #pragma unroll 4
        for (int d4 = 0; d4 < 16; ++d4) {
            float4 ra[4], rb[4];
            #pragma unroll
            for (int a = 0; a < 4; ++a) ra[a] = *(float4*)&qS[ty + 16 * a][d4 * 4];
            #pragma unroll
            for (int b2 = 0; b2 < 4; ++b2) rb[b2] = *(float4*)&kS[tx + 16 * b2][d4 * 4];
            #pragma unroll
            for (int a = 0; a < 4; ++a)
                #pragma unroll
                for (int b2 = 0; b2 < 4; ++b2)
                    lacc[a][b2] += ra[a].x * rb[b2].x + ra[a].y * rb[b2].y
                                 + ra[a].z * rb[b2].z + ra[a].w * rb[b2].w;
        }
        // mask + store scaled logits
        #pragma unroll
        for (int a = 0; a < 4; ++a) {
            int qq = ty + 16 * a;
            #pragma unroll
            for (int b2 = 0; b2 < 4; ++b2) {
                int s = tx + 16 * b2;
                bool ok = (T0 + qq + 1) >= send[s];
                sS[qq][s] = ok ? lacc[a][b2] * 0.125f : -1e30f;
            }
        }
        __syncthreads();

        // pass 1: rowmax
        const int row = tid >> 2, part = tid & 3;
        float mx = -3e38f;
        for (int s = part; s < 64; s += 4) mx = fmaxf(mx, sS[row][s]);
        red[row][part] = mx;
        __syncthreads();
        if (tid < 64) {
            float rmax = fmaxf(fmaxf(red[tid][0], red[tid][1]), fmaxf(red[tid][2], red[tid][3]));
            float mold = mrow[tid];
            float mnew = fmaxf(mold, rmax);
            arow[tid] = __expf(mold - mnew);
            mrow[tid] = mnew;
        }
        __syncthreads();

        // pass 2: exp + rowsum
        float sum = 0.f;
        const float mn = mrow[row];
        for (int s = part; s < 64; s += 4) {
            float v0 = sS[row][s];
            float p = v0 > -1e29f ? __expf(v0 - mn) : 0.f;
            sS[row][s] = p;
            sum += p;
        }
        red[row][part] = sum;
        __syncthreads();
        if (tid < 64)
            lrow[tid] = arow[tid] * lrow[tid] + red[tid][0] + red[tid][1] + red[tid][2] + red[tid][3];
        // rescale O
        #pragma unroll
        for (int a = 0; a < 4; ++a) {
            float al = arow[ty + 16 * a];
            #pragma unroll
            for (int b2 = 0; b2 < 4; ++b2) acc[a][b2] *= al;
        }

        // PV: acc[q][d] += sum_s P[q][s] * V[s][d]
        #pragma unroll 4
        for (int s4 = 0; s4 < 16; ++s4) {
            float4 pa[4], vb[4];
            #pragma unroll
            for (int a = 0; a < 4; ++a) pa[a] = *(float4*)&sS[ty + 16 * a][s4 * 4];
            #pragma unroll
            for (int j = 0; j < 4; ++j) vb[j] = *(float4*)&vS[s4 * 4 + j][tx * 4];
            #pragma unroll
            for (int a = 0; a < 4; ++a) {
                acc[a][0] += pa[a].x * vb[0].x + pa[a].y * vb[1].x + pa[a].z * vb[2].x + pa[a].w * vb[3].x;
                acc[a][1] += pa[a].x * vb[0].y + pa[a].y * vb[1].y + pa[a].z * vb[2].y + pa[a].w * vb[3].y;
                acc[a][2] += pa[a].x * vb[0].z + pa[a].y * vb[1].z + pa[a].z * vb[2].z + pa[a].w * vb[3].z;
                acc[a][3] += pa[a].x * vb[0].w + pa[a].y * vb[1].w + pa[a].z * vb[2].w + pa[a].w * vb[3].w;
            }
        }
    }

    __syncthreads();   // last PV done before red reuse

    // tail column
    {
        const int row = tid >> 2, part = tid & 3;
        float dp = 0.f;
        const float* ktr = &Ktail[((size_t)(T0 + row) * NHEAD + h) * 64];
        for (int d = part; d < 64; d += 4) dp += qS[row][d] * ktr[d];
        red[row][part] = dp;
    }
    __syncthreads();
    if (tid < 64) {
        float tl = (red[tid][0] + red[tid][1] + red[tid][2] + red[tid][3]) * 0.125f;
        float mold = mrow[tid];
        float mf = fmaxf(mold, tl);
        float al = __expf(mold - mf);
        float pt = __expf(tl - mf);
        float lf = al * lrow[tid] + pt;
        arow[tid] = al;
        lrow[tid] = pt / lf;    // pt * inv
        mrow[tid] = 1.f / lf;   // inv
    }
    __syncthreads();

    // epilogue: out = acc*al*inv + (pt*inv)*Vtail
    #pragma unroll
    for (int a = 0; a < 4; ++a) {
        int qq = ty + 16 * a;
        float al_inv = arow[qq] * mrow[qq];
        float ptinv = lrow[qq];
        size_t base = ((size_t)(T0 + qq) * NHEAD + h) * 64 + tx * 4;
        float4 vt = *(const float4*)&Vtail[base];
        float4 o;
        o.x = acc[a][0] * al_inv + ptinv * vt.x;
        o.y = acc[a][1] * al_inv + ptinv * vt.y;
        o.z = acc[a][2] * al_inv + ptinv * vt.z;
        o.w = acc[a][3] * al_inv + ptinv * vt.w;
        *(float4*)&attout[base] = o;
    }
}

extern "C" void kernel_launch(void* const* d_in, const int* in_sizes, int n_in,
                              void* d_out, int out_size, void* d_ws, size_t ws_size,
                              hipStream_t stream)
{
    const float* x   = (const float*)d_in[0];
    const float* Wq  = (const float*)d_in[1];
    const float* Wk  = (const float*)d_in[2];
    const float* Wv  = (const float*)d_in[3];
    const float* Wks = (const float*)d_in[4];
    const float* bks = (const float*)d_in[5];
    const float* Wvs = (const float*)d_in[6];
    const float* bvs = (const float*)d_in[7];
    const float* Wc  = (const float*)d_in[8];
    const float* bc  = (const float*)d_in[9];
    float* out = (float*)d_out;

    float* ws = (float*)d_ws;
    const size_t TC = (size_t)TLEN * CDIM;
    float* q      = ws;
    float* k      = q + TC;
    float* v      = k + TC;
    float* kkv    = v + TC;
    float* vvv    = kkv + TC;
    float* Kt     = vvv + TC;
    float* Vt     = Kt + TC;
    float* Kset   = Vt + TC;
    float* Vset   = Kset + (size_t)NSETS * CDIM;
    float* attout = Vset + (size_t)NSETS * CDIM;

    dim3 gg(CDIM / 64, TLEN / 64);
    gemm64<1, 0><<<gg, 256, 0, stream>>>(x, Wq, nullptr, q, TLEN, CDIM, CDIM);
    gemm64<1, 0><<<gg, 256, 0, stream>>>(x, Wk, nullptr, k, TLEN, CDIM, CDIM);
    gemm64<0, 0><<<gg, 256, 0, stream>>>(x, Wv, nullptr, v, TLEN, CDIM, CDIM);

    map_kv<<<(TLEN * NHEAD) / 64, 256, 0, stream>>>(k, v, Wks, Wvs, kkv, vvv);

    tail_kernel<<<(TLEN * CDIM) / 256, 256, 0, stream>>>(kkv, vvv, bks, bvs, Kt, Vt);
    set_kernel<<<NSETS * NHEAD, 64, 0, stream>>>(kkv, vvv, bks, bvs, Kset, Vset);

    attn_tiled<<<TLEN / 64 * NHEAD, 256, 0, stream>>>(q, Kset, Vset, Kt, Vt, attout);

    gemm64<0, 1><<<gg, 256, 0, stream>>>(attout, Wc, bc, out, TLEN, CDIM, CDIM);
}

// Round 3
// 924.271 us; speedup vs baseline: 1.8182x; 1.2682x over previous
//
#include <hip/hip_runtime.h>
#include <cstdint>

#define NHEAD 12
#define TLEN 2048
#define CDIM 768
#define NSETS 1023   // 512+256+128+64+32+16+8+4+2+1

typedef __attribute__((ext_vector_type(8))) short short8;   // 8 bf16 (4 VGPRs)
typedef __attribute__((ext_vector_type(4))) float f32x4;

__device__ __forceinline__ float elu1(float x) { return x > 0.f ? x + 1.f : __expf(x); }

// pack truncated-bf16 of two floats: low half = bf16(a), high half = bf16(b)
__device__ __forceinline__ unsigned pack2_bf16_trunc(float a, float b) {
    unsigned ua = __float_as_uint(a), ub = __float_as_uint(b);
    return __builtin_amdgcn_perm(ub, ua, 0x07060302);
}

__device__ __forceinline__ short8 mk_short8(unsigned a, unsigned b, unsigned c, unsigned d) {
    union { unsigned u[4]; short8 s; } x;
    x.u[0] = a; x.u[1] = b; x.u[2] = c; x.u[3] = d;
    return x.s;
}

// ---------- generic 64x64-tile f32 GEMM: C = A[M,K] @ B[K,N] (+bias) (+elu+1) ----------
template<int ACT, int BIAS>
__global__ __launch_bounds__(256) void gemm64(
    const float* __restrict__ A, const float* __restrict__ B,
    const float* __restrict__ bias, float* __restrict__ Cmat,
    int M, int N, int K)
{
    __shared__ float As[64][17];
    __shared__ float Bs[16][65];
    const int tid = threadIdx.x;
    const int tx = tid & 15, ty = tid >> 4;
    const int m0 = blockIdx.y * 64, n0 = blockIdx.x * 64;
    float acc[4][4] = {};
    for (int k0 = 0; k0 < K; k0 += 16) {
        #pragma unroll
        for (int i = 0; i < 4; ++i) {
            int e = tid + i * 256;
            int ar = e >> 4, ac = e & 15;
            As[ar][ac] = A[(size_t)(m0 + ar) * K + k0 + ac];
            int br = e >> 6, bc = e & 63;
            Bs[br][bc] = B[(size_t)(k0 + br) * N + n0 + bc];
        }
        __syncthreads();
        #pragma unroll
        for (int kk = 0; kk < 16; ++kk) {
            float ra[4], rb[4];
            #pragma unroll
            for (int a = 0; a < 4; ++a) ra[a] = As[ty + a * 16][kk];
            #pragma unroll
            for (int b = 0; b < 4; ++b) rb[b] = Bs[kk][tx + b * 16];
            #pragma unroll
            for (int a = 0; a < 4; ++a)
                #pragma unroll
                for (int b = 0; b < 4; ++b)
                    acc[a][b] += ra[a] * rb[b];
        }
        __syncthreads();
    }
    #pragma unroll
    for (int a = 0; a < 4; ++a) {
        int m = m0 + ty + a * 16;
        #pragma unroll
        for (int b = 0; b < 4; ++b) {
            int n = n0 + tx + b * 16;
            float v = acc[a][b];
            if (BIAS) v += bias[n];
            if (ACT) v = elu1(v);
            Cmat[(size_t)m * N + n] = v;
        }
    }
}

// ---------- prep: split-transpose Wks|Wvs into bf16 hi/lo planes ----------
// Whi/Wlo layout: [n=0..127][kk=0..4095], n<64 -> Wks col n, n>=64 -> Wvs col n-64
__global__ __launch_bounds__(256) void prep_w(
    const float* __restrict__ Wks, const float* __restrict__ Wvs,
    unsigned short* __restrict__ Whi, unsigned short* __restrict__ Wlo)
{
    const int idx = blockIdx.x * 256 + threadIdx.x;    // 128*4096
    const int n = idx >> 12, kk = idx & 4095;
    float f = (n < 64) ? Wks[(size_t)kk * 64 + n] : Wvs[(size_t)kk * 64 + (n - 64)];
    unsigned u = __float_as_uint(f);
    float d = f - __uint_as_float(u & 0xffff0000u);
    Whi[idx] = (unsigned short)(u >> 16);
    Wlo[idx] = (unsigned short)(__float_as_uint(d) >> 16);
}

// ---------- MFMA mapped features: kkv[p,n] = sum_{i,j} k[p,i] v[p,j] Wks[i*64+j,n] ----------
// split-bf16 3-MFMA: p=k*v (f32) -> phi+plo; W -> Whi+Wlo; out = phi*Whi + plo*Whi + phi*Wlo
// block: 64 positions x 128 outputs (n<64 -> kkv, n>=64 -> vvv). 4 waves: (m-half, n-half).
__global__ __launch_bounds__(256, 3) void map_mfma(
    const float* __restrict__ kbuf, const float* __restrict__ vbuf,
    const unsigned short* __restrict__ Whi, const unsigned short* __restrict__ Wlo,
    float* __restrict__ kkv, float* __restrict__ vvv)
{
    __shared__ float kS[64][68];                // 17408 B
    __shared__ unsigned short BhS[128][72];     // 18432 B
    __shared__ unsigned short BlS[128][72];     // 18432 B  (total 54272 -> 3 blocks/CU)

    const int tid = threadIdx.x;
    const int p0 = blockIdx.x * 64;
    const int wave = tid >> 6, lane = tid & 63;
    const int lane15 = lane & 15, quad = lane >> 4;
    const int m0 = (wave & 1) * 32;       // position half
    const int n0 = (wave >> 1) * 64;      // output half (0 -> kkv map, 64 -> vvv map)

    // stage kS [pos][i]
    #pragma unroll
    for (int u = 0; u < 4; ++u) {
        int c = tid + u * 256;            // 1024 float4 chunks
        int row = c >> 4, col = (c & 15) * 4;
        *(float4*)&kS[row][col] = *(const float4*)&kbuf[(size_t)(p0 + row) * 64 + col];
    }

    // v values this lane will ever need: 2 positions x 16 j's (fixed by quad)
    float vr[2][2][8];
    #pragma unroll
    for (int ms = 0; ms < 2; ++ms) {
        const size_t pbase = (size_t)(p0 + m0 + ms * 16 + lane15) * 64;
        #pragma unroll
        for (int ks = 0; ks < 2; ++ks) {
            *(float4*)&vr[ms][ks][0] = *(const float4*)&vbuf[pbase + ks * 32 + quad * 8];
            *(float4*)&vr[ms][ks][4] = *(const float4*)&vbuf[pbase + ks * 32 + quad * 8 + 4];
        }
    }

    f32x4 acc[2][4];
    #pragma unroll
    for (int ms = 0; ms < 2; ++ms)
        #pragma unroll
        for (int ns = 0; ns < 4; ++ns)
            acc[ms][ns] = (f32x4){0.f, 0.f, 0.f, 0.f};

    for (int i = 0; i < 64; ++i) {
        __syncthreads();   // previous-iter B reads done (also covers kS staging on i=0)
        // stage B hi/lo slice: rows n=0..127, cols = W rows i*64..i*64+63
        #pragma unroll
        for (int u = 0; u < 4; ++u) {
            int c = tid + u * 256;        // 1024 16B chunks per plane
            int n = c >> 3, off = (c & 7) * 8;
            const size_t g = (size_t)n * 4096 + i * 64 + off;
            *(uint4*)&BhS[n][off] = *(const uint4*)&Whi[g];
            *(uint4*)&BlS[n][off] = *(const uint4*)&Wlo[g];
        }
        __syncthreads();

        float kf[2];
        kf[0] = kS[m0 + lane15][i];
        kf[1] = kS[m0 + 16 + lane15][i];

        // generate A fragments (hi/lo) in registers
        short8 ahi[2][2], alo[2][2];
        #pragma unroll
        for (int ms = 0; ms < 2; ++ms) {
            #pragma unroll
            for (int ks = 0; ks < 2; ++ks) {
                unsigned hp[4], lp[4];
                #pragma unroll
                for (int jp = 0; jp < 4; ++jp) {
                    float p1 = kf[ms] * vr[ms][ks][jp * 2];
                    float p2 = kf[ms] * vr[ms][ks][jp * 2 + 1];
                    unsigned u1 = __float_as_uint(p1), u2 = __float_as_uint(p2);
                    float d1 = p1 - __uint_as_float(u1 & 0xffff0000u);
                    float d2 = p2 - __uint_as_float(u2 & 0xffff0000u);
                    hp[jp] = __builtin_amdgcn_perm(u2, u1, 0x07060302);
                    lp[jp] = pack2_bf16_trunc(d1, d2);
                }
                ahi[ms][ks] = mk_short8(hp[0], hp[1], hp[2], hp[3]);
                alo[ms][ks] = mk_short8(lp[0], lp[1], lp[2], lp[3]);
            }
        }

        #pragma unroll
        for (int ks = 0; ks < 2; ++ks) {
            #pragma unroll
            for (int ns = 0; ns < 4; ++ns) {
                const int brow = n0 + ns * 16 + lane15;
                const int bcol = ks * 32 + quad * 8;
                short8 bh = *(const short8*)&BhS[brow][bcol];
                short8 bl = *(const short8*)&BlS[brow][bcol];
                #pragma unroll
                for (int ms = 0; ms < 2; ++ms) {
                    acc[ms][ns] = __builtin_amdgcn_mfma_f32_16x16x32_bf16(ahi[ms][ks], bh, acc[ms][ns], 0, 0, 0);
                    acc[ms][ns] = __builtin_amdgcn_mfma_f32_16x16x32_bf16(alo[ms][ks], bh, acc[ms][ns], 0, 0, 0);
                    acc[ms][ns] = __builtin_amdgcn_mfma_f32_16x16x32_bf16(ahi[ms][ks], bl, acc[ms][ns], 0, 0, 0);
                }
            }
        }
    }

    // epilogue: C/D layout col=lane&15, row=quad*4+reg
    float* dst = (wave >> 1) ? vvv : kkv;
    #pragma unroll
    for (int ms = 0; ms < 2; ++ms) {
        #pragma unroll
        for (int ns = 0; ns < 4; ++ns) {
            #pragma unroll
            for (int r = 0; r < 4; ++r) {
                int p = p0 + m0 + ms * 16 + quad * 4 + r;
                int col = ns * 16 + lane15;
                dst[(size_t)p * 64 + col] = acc[ms][ns][r];
            }
        }
    }
}

// ---------- tail features ----------
__global__ __launch_bounds__(256) void tail_kernel(
    const float* __restrict__ kkv, const float* __restrict__ vvv,
    const float* __restrict__ bks, const float* __restrict__ bvs,
    float* __restrict__ Kt, float* __restrict__ Vt)
{
    const int idx = blockIdx.x * 256 + threadIdx.x;
    const int t = idx / CDIM;
    const int r = idx % CDIM;
    const int d = r & 63;
    const int t0 = t & ~3;
    float ak = bks[d], av = bvs[d];
    for (int tt = t0; tt <= t; ++tt) {
        ak += kkv[(size_t)tt * CDIM + r];
        av += vvv[(size_t)tt * CDIM + r];
    }
    Kt[idx] = ak;
    Vt[idx] = av;
}

// ---------- set features ----------
__global__ __launch_bounds__(64) void set_kernel(
    const float* __restrict__ kkv, const float* __restrict__ vvv,
    const float* __restrict__ bks, const float* __restrict__ bvs,
    float* __restrict__ Kset, float* __restrict__ Vset)
{
    const int s = blockIdx.x / NHEAD;
    const int h = blockIdx.x % NHEAD;
    const int d = threadIdx.x;
    int l = 2, n = 512, rem = s;
    while (rem >= n) { rem -= n; n >>= 1; ++l; }
    const int t0 = rem << l;
    const int len = 1 << l;
    float ak = bks[d], av = bvs[d];
    const float* pk = kkv + (size_t)t0 * CDIM + h * 64 + d;
    const float* pv = vvv + (size_t)t0 * CDIM + h * 64 + d;
    for (int i = 0; i < len; ++i) {
        ak += pk[(size_t)i * CDIM];
        av += pv[(size_t)i * CDIM];
    }
    const size_t o = ((size_t)s * NHEAD + h) * 64 + d;
    Kset[o] = ak;
    Vset[o] = av;
}

// ---------- tiled flash-style attention ----------
__global__ __launch_bounds__(256) void attn_tiled(
    const float* __restrict__ qbuf, const float* __restrict__ Kset,
    const float* __restrict__ Vset, const float* __restrict__ Ktail,
    const float* __restrict__ Vtail, float* __restrict__ attout)
{
    __shared__ float qS[64][68];
    __shared__ float kS[64][68];
    __shared__ float vS[64][68];
    __shared__ float sS[64][68];
    __shared__ float mrow[64], lrow[64], arow[64];
    __shared__ float red[64][4];
    __shared__ int   sid[64];
    __shared__ int   send[64];

    const int tid = threadIdx.x;
    const int b   = blockIdx.x / NHEAD;
    const int h   = blockIdx.x % NHEAD;
    const int T0  = b * 64;
    const int tx  = tid & 15, ty = tid >> 4;

    const int Tend = T0 + 64;
    const int LOFF[10] = {0, 512, 768, 896, 960, 992, 1008, 1016, 1020, 1022};
    int cnt[10], pfx[10], Vtot = 0;
    #pragma unroll
    for (int li = 0; li < 10; ++li) { cnt[li] = Tend >> (li + 2); pfx[li] = Vtot; Vtot += cnt[li]; }

    #pragma unroll
    for (int i = 0; i < 4; ++i) {
        int qi = (tid >> 4) + 16 * i;
        int d4 = tid & 15;
        *(float4*)&qS[qi][d4 * 4] =
            *(const float4*)&qbuf[((size_t)(T0 + qi) * NHEAD + h) * 64 + d4 * 4];
    }
    if (tid < 64) { mrow[tid] = -1e30f; lrow[tid] = 0.f; }

    float acc[4][4] = {};
    const int ntiles = (Vtot + 63) >> 6;

    for (int tile = 0; tile < ntiles; ++tile) {
        __syncthreads();

        if (tid < 64) {
            int j = tile * 64 + tid;
            int s_ = 0, e_ = 0x7fffffff;
            if (j < Vtot) {
                int li = 0;
                #pragma unroll
                for (int u = 1; u < 10; ++u) if (j >= pfx[u]) li = u;
                int idx = j - pfx[li];
                s_ = LOFF[li] + idx;
                e_ = (idx + 1) << (li + 2);
            }
            sid[tid] = s_; send[tid] = e_;
        }
        __syncthreads();

        #pragma unroll
        for (int i = 0; i < 4; ++i) {
            int s  = (tid >> 4) + 16 * i;
            int d4 = tid & 15;
            size_t base = ((size_t)sid[s] * NHEAD + h) * 64 + d4 * 4;
            *(float4*)&kS[s][d4 * 4] = *(const float4*)&Kset[base];
            *(float4*)&vS[s][d4 * 4] = *(const float4*)&Vset[base];
        }
        __syncthreads();

        float lacc[4][4] = {};
        #pragma unroll 4
        for (int d4 = 0; d4 < 16; ++d4) {
            float4 ra[4], rb[4];
            #pragma unroll
            for (int a = 0; a < 4; ++a) ra[a] = *(float4*)&qS[ty + 16 * a][d4 * 4];
            #pragma unroll
            for (int b2 = 0; b2 < 4; ++b2) rb[b2] = *(float4*)&kS[tx + 16 * b2][d4 * 4];
            #pragma unroll
            for (int a = 0; a < 4; ++a)
                #pragma unroll
                for (int b2 = 0; b2 < 4; ++b2)
                    lacc[a][b2] += ra[a].x * rb[b2].x + ra[a].y * rb[b2].y
                                 + ra[a].z * rb[b2].z + ra[a].w * rb[b2].w;
        }
        #pragma unroll
        for (int a = 0; a < 4; ++a) {
            int qq = ty + 16 * a;
            #pragma unroll
            for (int b2 = 0; b2 < 4; ++b2) {
                int s = tx + 16 * b2;
                bool ok = (T0 + qq + 1) >= send[s];
                sS[qq][s] = ok ? lacc[a][b2] * 0.125f : -1e30f;
            }
        }
        __syncthreads();

        const int row = tid >> 2, part = tid & 3;
        float mx = -3e38f;
        for (int s = part; s < 64; s += 4) mx = fmaxf(mx, sS[row][s]);
        red[row][part] = mx;
        __syncthreads();
        if (tid < 64) {
            float rmax = fmaxf(fmaxf(red[tid][0], red[tid][1]), fmaxf(red[tid][2], red[tid][3]));
            float mold = mrow[tid];
            float mnew = fmaxf(mold, rmax);
            arow[tid] = __expf(mold - mnew);
            mrow[tid] = mnew;
        }
        __syncthreads();

        float sum = 0.f;
        const float mn = mrow[row];
        for (int s = part; s < 64; s += 4) {
            float v0 = sS[row][s];
            float p = v0 > -1e29f ? __expf(v0 - mn) : 0.f;
            sS[row][s] = p;
            sum += p;
        }
        red[row][part] = sum;
        __syncthreads();
        if (tid < 64)
            lrow[tid] = arow[tid] * lrow[tid] + red[tid][0] + red[tid][1] + red[tid][2] + red[tid][3];
        #pragma unroll
        for (int a = 0; a < 4; ++a) {
            float al = arow[ty + 16 * a];
            #pragma unroll
            for (int b2 = 0; b2 < 4; ++b2) acc[a][b2] *= al;
        }

        #pragma unroll 4
        for (int s4 = 0; s4 < 16; ++s4) {
            float4 pa[4], vb[4];
            #pragma unroll
            for (int a = 0; a < 4; ++a) pa[a] = *(float4*)&sS[ty + 16 * a][s4 * 4];
            #pragma unroll
            for (int j = 0; j < 4; ++j) vb[j] = *(float4*)&vS[s4 * 4 + j][tx * 4];
            #pragma unroll
            for (int a = 0; a < 4; ++a) {
                acc[a][0] += pa[a].x * vb[0].x + pa[a].y * vb[1].x + pa[a].z * vb[2].x + pa[a].w * vb[3].x;
                acc[a][1] += pa[a].x * vb[0].y + pa[a].y * vb[1].y + pa[a].z * vb[2].y + pa[a].w * vb[3].y;
                acc[a][2] += pa[a].x * vb[0].z + pa[a].y * vb[1].z + pa[a].z * vb[2].z + pa[a].w * vb[3].z;
                acc[a][3] += pa[a].x * vb[0].w + pa[a].y * vb[1].w + pa[a].z * vb[2].w + pa[a].w * vb[3].w;
            }
        }
    }

    __syncthreads();

    {
        const int row = tid >> 2, part = tid & 3;
        float dp = 0.f;
        const float* ktr = &Ktail[((size_t)(T0 + row) * NHEAD + h) * 64];
        for (int d = part; d < 64; d += 4) dp += qS[row][d] * ktr[d];
        red[row][part] = dp;
    }
    __syncthreads();
    if (tid < 64) {
        float tl = (red[tid][0] + red[tid][1] + red[tid][2] + red[tid][3]) * 0.125f;
        float mold = mrow[tid];
        float mf = fmaxf(mold, tl);
        float al = __expf(mold - mf);
        float pt = __expf(tl - mf);
        float lf = al * lrow[tid] + pt;
        arow[tid] = al;
        lrow[tid] = pt / lf;
        mrow[tid] = 1.f / lf;
    }
    __syncthreads();

    #pragma unroll
    for (int a = 0; a < 4; ++a) {
        int qq = ty + 16 * a;
        float al_inv = arow[qq] * mrow[qq];
        float ptinv = lrow[qq];
        size_t base = ((size_t)(T0 + qq) * NHEAD + h) * 64 + tx * 4;
        float4 vt = *(const float4*)&Vtail[base];
        float4 o;
        o.x = acc[a][0] * al_inv + ptinv * vt.x;
        o.y = acc[a][1] * al_inv + ptinv * vt.y;
        o.z = acc[a][2] * al_inv + ptinv * vt.z;
        o.w = acc[a][3] * al_inv + ptinv * vt.w;
        *(float4*)&attout[base] = o;
    }
}

extern "C" void kernel_launch(void* const* d_in, const int* in_sizes, int n_in,
                              void* d_out, int out_size, void* d_ws, size_t ws_size,
                              hipStream_t stream)
{
    const float* x   = (const float*)d_in[0];
    const float* Wq  = (const float*)d_in[1];
    const float* Wk  = (const float*)d_in[2];
    const float* Wv  = (const float*)d_in[3];
    const float* Wks = (const float*)d_in[4];
    const float* bks = (const float*)d_in[5];
    const float* Wvs = (const float*)d_in[6];
    const float* bvs = (const float*)d_in[7];
    const float* Wc  = (const float*)d_in[8];
    const float* bc  = (const float*)d_in[9];
    float* out = (float*)d_out;

    float* ws = (float*)d_ws;
    const size_t TC = (size_t)TLEN * CDIM;
    float* q      = ws;
    float* k      = q + TC;
    float* v      = k + TC;
    float* kkv    = v + TC;
    float* vvv    = kkv + TC;
    float* Kt     = vvv + TC;
    float* Vt     = Kt + TC;
    float* Kset   = Vt + TC;
    float* Vset   = Kset + (size_t)NSETS * CDIM;
    float* attout = Vset + (size_t)NSETS * CDIM;
    // Whi/Wlo (2 MB total) aliased onto attout (6 MB): dead before attn writes it
    unsigned short* Whi = (unsigned short*)attout;
    unsigned short* Wlo = Whi + (size_t)128 * 4096;

    dim3 gg(CDIM / 64, TLEN / 64);
    gemm64<1, 0><<<gg, 256, 0, stream>>>(x, Wq, nullptr, q, TLEN, CDIM, CDIM);
    gemm64<1, 0><<<gg, 256, 0, stream>>>(x, Wk, nullptr, k, TLEN, CDIM, CDIM);
    gemm64<0, 0><<<gg, 256, 0, stream>>>(x, Wv, nullptr, v, TLEN, CDIM, CDIM);

    prep_w<<<2048, 256, 0, stream>>>(Wks, Wvs, Whi, Wlo);

    map_mfma<<<(TLEN * NHEAD) / 64, 256, 0, stream>>>(k, v, Whi, Wlo, kkv, vvv);

    tail_kernel<<<(TLEN * CDIM) / 256, 256, 0, stream>>>(kkv, vvv, bks, bvs, Kt, Vt);
    set_kernel<<<NSETS * NHEAD, 64, 0, stream>>>(kkv, vvv, bks, bvs, Kset, Vset);

    attn_tiled<<<TLEN / 64 * NHEAD, 256, 0, stream>>>(q, Kset, Vset, Kt, Vt, attout);

    gemm64<0, 1><<<gg, 256, 0, stream>>>(attout, Wc, bc, out, TLEN, CDIM, CDIM);
}

// Round 5
// 767.948 us; speedup vs baseline: 2.1883x; 1.2036x over previous
//
#include <hip/hip_runtime.h>
#include <cstdint>

#define NHEAD 12
#define TLEN 2048
#define CDIM 768
#define NSETS 1023   // 512+256+128+64+32+16+8+4+2+1

typedef __attribute__((ext_vector_type(8))) _Float16 half8;
typedef __attribute__((ext_vector_type(2))) __fp16 fp16x2;
typedef __attribute__((ext_vector_type(4))) float f32x4;

__device__ __forceinline__ float elu1(float x) { return x > 0.f ? x + 1.f : __expf(x); }

// ---------- generic 64x64-tile f32 GEMM: C = A[M,K] @ B[K,N] (+bias) (+elu+1) ----------
template<int ACT, int BIAS>
__global__ __launch_bounds__(256) void gemm64(
    const float* __restrict__ A, const float* __restrict__ B,
    const float* __restrict__ bias, float* __restrict__ Cmat,
    int M, int N, int K)
{
    __shared__ float As[64][17];
    __shared__ float Bs[16][65];
    const int tid = threadIdx.x;
    const int tx = tid & 15, ty = tid >> 4;
    const int m0 = blockIdx.y * 64, n0 = blockIdx.x * 64;
    float acc[4][4] = {};
    for (int k0 = 0; k0 < K; k0 += 16) {
        #pragma unroll
        for (int i = 0; i < 4; ++i) {
            int e = tid + i * 256;
            int ar = e >> 4, ac = e & 15;
            As[ar][ac] = A[(size_t)(m0 + ar) * K + k0 + ac];
            int br = e >> 6, bc = e & 63;
            Bs[br][bc] = B[(size_t)(k0 + br) * N + n0 + bc];
        }
        __syncthreads();
        #pragma unroll
        for (int kk = 0; kk < 16; ++kk) {
            float ra[4], rb[4];
            #pragma unroll
            for (int a = 0; a < 4; ++a) ra[a] = As[ty + a * 16][kk];
            #pragma unroll
            for (int b = 0; b < 4; ++b) rb[b] = Bs[kk][tx + b * 16];
            #pragma unroll
            for (int a = 0; a < 4; ++a)
                #pragma unroll
                for (int b = 0; b < 4; ++b)
                    acc[a][b] += ra[a] * rb[b];
        }
        __syncthreads();
    }
    #pragma unroll
    for (int a = 0; a < 4; ++a) {
        int m = m0 + ty + a * 16;
        #pragma unroll
        for (int b = 0; b < 4; ++b) {
            int n = n0 + tx + b * 16;
            float v = acc[a][b];
            if (BIAS) v += bias[n];
            if (ACT) v = elu1(v);
            Cmat[(size_t)m * N + n] = v;
        }
    }
}

// ---------- prep: W -> f16 fragment-major blob ----------
// blob chunk index for (i, ks, nsg): (((i*2+ks)*8+nsg)*64 + lane)*8 + j  halfs
// element = W[kk = i*64 + ks*32 + quad*8 + j][n = nsg*16 + lane15], lane = quad*16+lane15
// n<64 -> Wks col n ; n>=64 -> Wvs col n-64
__global__ __launch_bounds__(256) void prep_w(
    const float* __restrict__ Wks, const float* __restrict__ Wvs,
    _Float16* __restrict__ Wblob)
{
    const int idx = blockIdx.x * 256 + threadIdx.x;   // 4096*128
    const int kk = idx >> 7, n = idx & 127;
    float f = (n < 64) ? Wks[(size_t)kk * 64 + n] : Wvs[(size_t)kk * 64 + (n - 64)];
    const int i = kk >> 6, kl = kk & 63;
    const int ks = kl >> 5, quad = (kl >> 3) & 3, j = kl & 7;
    const int nsg = n >> 4, lane15 = n & 15;
    const int lane = quad * 16 + lane15;
    const size_t off = ((size_t)(((i * 2 + ks) * 8 + nsg)) * 64 + lane) * 8 + j;
    Wblob[off] = (_Float16)f;   // RNE
}

// ---------- MFMA mapped features, f16 exact-split, direct-global B, no K-loop barriers ----
// block: 32 positions x 128 outputs; 4 waves, wave w covers nsg {2w, 2w+1}
// out = (phi + plo) @ W_f16 ; phi = f16_rtz(k*v), plo = f16_rtz(k*v - phi)
__global__ __launch_bounds__(256, 3) void map_f16(
    const float* __restrict__ kbuf, const float* __restrict__ vbuf,
    const _Float16* __restrict__ Wblob,
    float* __restrict__ kkv, float* __restrict__ vvv)
{
    __shared__ float kS[32][68];

    const int tid = threadIdx.x;
    const int p0 = blockIdx.x * 32;
    const int wave = tid >> 6, lane = tid & 63;
    const int lane15 = lane & 15, quad = lane >> 4;

    // stage kS [pos 0..31][i 0..63]
    #pragma unroll
    for (int u = 0; u < 2; ++u) {
        int c = tid + u * 256;                 // 512 float4 chunks
        int row = c >> 4, col = (c & 15) * 4;
        *(float4*)&kS[row][col] = *(const float4*)&kbuf[(size_t)(p0 + row) * 64 + col];
    }

    // v values this lane needs: 2 ms x 2 ks x 8 j
    float vr[2][2][8];
    #pragma unroll
    for (int ms = 0; ms < 2; ++ms) {
        const size_t pbase = (size_t)(p0 + ms * 16 + lane15) * 64;
        #pragma unroll
        for (int ks = 0; ks < 2; ++ks) {
            *(float4*)&vr[ms][ks][0] = *(const float4*)&vbuf[pbase + ks * 32 + quad * 8];
            *(float4*)&vr[ms][ks][4] = *(const float4*)&vbuf[pbase + ks * 32 + quad * 8 + 4];
        }
    }

    __syncthreads();   // kS ready; no further barriers

    const half8* __restrict__ Wc = (const half8*)Wblob;   // chunk = ((i*2+ks)*8+nsg)*64 + lane

    f32x4 acc[2][2];
    #pragma unroll
    for (int ms = 0; ms < 2; ++ms)
        #pragma unroll
        for (int ns = 0; ns < 2; ++ns)
            acc[ms][ns] = (f32x4){0.f, 0.f, 0.f, 0.f};

    half8 bA[4], bB[4];
    float kA[2], kB[2];

    auto loadB = [&](half8* b, int i) {
        #pragma unroll
        for (int ks = 0; ks < 2; ++ks)
            #pragma unroll
            for (int nsl = 0; nsl < 2; ++nsl)
                b[ks * 2 + nsl] = Wc[(size_t)((i * 2 + ks) * 8 + wave * 2 + nsl) * 64 + lane];
    };
    auto loadK = [&](float* kf, int i) {
        kf[0] = kS[lane15][i];
        kf[1] = kS[16 + lane15][i];
    };
    auto compute = [&](const half8* b, const float* kf) {
        #pragma unroll
        for (int ks = 0; ks < 2; ++ks) {
            half8 ah[2], al[2];
            #pragma unroll
            for (int ms = 0; ms < 2; ++ms) {
                union { fp16x2 h2[4]; half8 h8; } uh, ul;
                #pragma unroll
                for (int jp = 0; jp < 4; ++jp) {
                    float pa = kf[ms] * vr[ms][ks][2 * jp];
                    float pb = kf[ms] * vr[ms][ks][2 * jp + 1];
                    fp16x2 hh = __builtin_amdgcn_cvt_pkrtz(pa, pb);
                    uh.h2[jp] = hh;
                    ul.h2[jp] = __builtin_amdgcn_cvt_pkrtz(pa - (float)hh[0], pb - (float)hh[1]);
                }
                ah[ms] = uh.h8; al[ms] = ul.h8;
            }
            #pragma unroll
            for (int nsl = 0; nsl < 2; ++nsl) {
                half8 bb = b[ks * 2 + nsl];
                #pragma unroll
                for (int ms = 0; ms < 2; ++ms) {
                    acc[ms][nsl] = __builtin_amdgcn_mfma_f32_16x16x32_f16(ah[ms], bb, acc[ms][nsl], 0, 0, 0);
                    acc[ms][nsl] = __builtin_amdgcn_mfma_f32_16x16x32_f16(al[ms], bb, acc[ms][nsl], 0, 0, 0);
                }
            }
        }
    };

    loadB(bA, 0); loadK(kA, 0);
    for (int i = 0; i < 64; i += 2) {
        loadB(bB, i + 1); loadK(kB, i + 1);
        compute(bA, kA);
        if (i + 2 < 64) { loadB(bA, i + 2); loadK(kA, i + 2); }
        compute(bB, kB);
    }

    // epilogue: C/D layout col=lane15, row=quad*4+r
    float* dst = (wave >= 2) ? vvv : kkv;
    const int nbase = (wave & 1) * 32;
    #pragma unroll
    for (int ms = 0; ms < 2; ++ms) {
        #pragma unroll
        for (int nsl = 0; nsl < 2; ++nsl) {
            #pragma unroll
            for (int r = 0; r < 4; ++r) {
                int p = p0 + ms * 16 + quad * 4 + r;
                int col = nbase + nsl * 16 + lane15;
                dst[(size_t)p * 64 + col] = acc[ms][nsl][r];
            }
        }
    }
}

// ---------- tail features ----------
__global__ __launch_bounds__(256) void tail_kernel(
    const float* __restrict__ kkv, const float* __restrict__ vvv,
    const float* __restrict__ bks, const float* __restrict__ bvs,
    float* __restrict__ Kt, float* __restrict__ Vt)
{
    const int idx = blockIdx.x * 256 + threadIdx.x;
    const int t = idx / CDIM;
    const int r = idx % CDIM;
    const int d = r & 63;
    const int t0 = t & ~3;
    float ak = bks[d], av = bvs[d];
    for (int tt = t0; tt <= t; ++tt) {
        ak += kkv[(size_t)tt * CDIM + r];
        av += vvv[(size_t)tt * CDIM + r];
    }
    Kt[idx] = ak;
    Vt[idx] = av;
}

// ---------- set features ----------
__global__ __launch_bounds__(64) void set_kernel(
    const float* __restrict__ kkv, const float* __restrict__ vvv,
    const float* __restrict__ bks, const float* __restrict__ bvs,
    float* __restrict__ Kset, float* __restrict__ Vset)
{
    const int s = blockIdx.x / NHEAD;
    const int h = blockIdx.x % NHEAD;
    const int d = threadIdx.x;
    int l = 2, n = 512, rem = s;
    while (rem >= n) { rem -= n; n >>= 1; ++l; }
    const int t0 = rem << l;
    const int len = 1 << l;
    float ak = bks[d], av = bvs[d];
    const float* pk = kkv + (size_t)t0 * CDIM + h * 64 + d;
    const float* pv = vvv + (size_t)t0 * CDIM + h * 64 + d;
    for (int i = 0; i < len; ++i) {
        ak += pk[(size_t)i * CDIM];
        av += pv[(size_t)i * CDIM];
    }
    const size_t o = ((size_t)s * NHEAD + h) * 64 + d;
    Kset[o] = ak;
    Vset[o] = av;
}

// ---------- tiled flash-style attention ----------
__global__ __launch_bounds__(256) void attn_tiled(
    const float* __restrict__ qbuf, const float* __restrict__ Kset,
    const float* __restrict__ Vset, const float* __restrict__ Ktail,
    const float* __restrict__ Vtail, float* __restrict__ attout)
{
    __shared__ float qS[64][68];
    __shared__ float kS[64][68];
    __shared__ float vS[64][68];
    __shared__ float sS[64][68];
    __shared__ float mrow[64], lrow[64], arow[64];
    __shared__ float red[64][4];
    __shared__ int   sid[64];
    __shared__ int   send[64];

    const int tid = threadIdx.x;
    const int b   = blockIdx.x / NHEAD;
    const int h   = blockIdx.x % NHEAD;
    const int T0  = b * 64;
    const int tx  = tid & 15, ty = tid >> 4;

    const int Tend = T0 + 64;
    const int LOFF[10] = {0, 512, 768, 896, 960, 992, 1008, 1016, 1020, 1022};
    int cnt[10], pfx[10], Vtot = 0;
    #pragma unroll
    for (int li = 0; li < 10; ++li) { cnt[li] = Tend >> (li + 2); pfx[li] = Vtot; Vtot += cnt[li]; }

    #pragma unroll
    for (int i = 0; i < 4; ++i) {
        int qi = (tid >> 4) + 16 * i;
        int d4 = tid & 15;
        *(float4*)&qS[qi][d4 * 4] =
            *(const float4*)&qbuf[((size_t)(T0 + qi) * NHEAD + h) * 64 + d4 * 4];
    }
    if (tid < 64) { mrow[tid] = -1e30f; lrow[tid] = 0.f; }

    float acc[4][4] = {};
    const int ntiles = (Vtot + 63) >> 6;

    for (int tile = 0; tile < ntiles; ++tile) {
        __syncthreads();

        if (tid < 64) {
            int j = tile * 64 + tid;
            int s_ = 0, e_ = 0x7fffffff;
            if (j < Vtot) {
                int li = 0;
                #pragma unroll
                for (int u = 1; u < 10; ++u) if (j >= pfx[u]) li = u;
                int idx = j - pfx[li];
                s_ = LOFF[li] + idx;
                e_ = (idx + 1) << (li + 2);
            }
            sid[tid] = s_; send[tid] = e_;
        }
        __syncthreads();

        #pragma unroll
        for (int i = 0; i < 4; ++i) {
            int s  = (tid >> 4) + 16 * i;
            int d4 = tid & 15;
            size_t base = ((size_t)sid[s] * NHEAD + h) * 64 + d4 * 4;
            *(float4*)&kS[s][d4 * 4] = *(const float4*)&Kset[base];
            *(float4*)&vS[s][d4 * 4] = *(const float4*)&Vset[base];
        }
        __syncthreads();

        float lacc[4][4] = {};
        #pragma unroll 4
        for (int d4 = 0; d4 < 16; ++d4) {
            float4 ra[4], rb[4];
            #pragma unroll
            for (int a = 0; a < 4; ++a) ra[a] = *(float4*)&qS[ty + 16 * a][d4 * 4];
            #pragma unroll
            for (int b2 = 0; b2 < 4; ++b2) rb[b2] = *(float4*)&kS[tx + 16 * b2][d4 * 4];
            #pragma unroll
            for (int a = 0; a < 4; ++a)
                #pragma unroll
                for (int b2 = 0; b2 < 4; ++b2)
                    lacc[a][b2] += ra[a].x * rb[b2].x + ra[a].y * rb[b2].y
                                 + ra[a].z * rb[b2].z + ra[a].w * rb[b2].w;
        }
        #pragma unroll
        for (int a = 0; a < 4; ++a) {
            int qq = ty + 16 * a;
            #pragma unroll
            for (int b2 = 0; b2 < 4; ++b2) {
                int s = tx + 16 * b2;
                bool ok = (T0 + qq + 1) >= send[s];
                sS[qq][s] = ok ? lacc[a][b2] * 0.125f : -1e30f;
            }
        }
        __syncthreads();

        const int row = tid >> 2, part = tid & 3;
        float mx = -3e38f;
        for (int s = part; s < 64; s += 4) mx = fmaxf(mx, sS[row][s]);
        red[row][part] = mx;
        __syncthreads();
        if (tid < 64) {
            float rmax = fmaxf(fmaxf(red[tid][0], red[tid][1]), fmaxf(red[tid][2], red[tid][3]));
            float mold = mrow[tid];
            float mnew = fmaxf(mold, rmax);
            arow[tid] = __expf(mold - mnew);
            mrow[tid] = mnew;
        }
        __syncthreads();

        float sum = 0.f;
        const float mn = mrow[row];
        for (int s = part; s < 64; s += 4) {
            float v0 = sS[row][s];
            float p = v0 > -1e29f ? __expf(v0 - mn) : 0.f;
            sS[row][s] = p;
            sum += p;
        }
        red[row][part] = sum;
        __syncthreads();
        if (tid < 64)
            lrow[tid] = arow[tid] * lrow[tid] + red[tid][0] + red[tid][1] + red[tid][2] + red[tid][3];
        #pragma unroll
        for (int a = 0; a < 4; ++a) {
            float al = arow[ty + 16 * a];
            #pragma unroll
            for (int b2 = 0; b2 < 4; ++b2) acc[a][b2] *= al;
        }

        #pragma unroll 4
        for (int s4 = 0; s4 < 16; ++s4) {
            float4 pa[4], vb[4];
            #pragma unroll
            for (int a = 0; a < 4; ++a) pa[a] = *(float4*)&sS[ty + 16 * a][s4 * 4];
            #pragma unroll
            for (int j = 0; j < 4; ++j) vb[j] = *(float4*)&vS[s4 * 4 + j][tx * 4];
            #pragma unroll
            for (int a = 0; a < 4; ++a) {
                acc[a][0] += pa[a].x * vb[0].x + pa[a].y * vb[1].x + pa[a].z * vb[2].x + pa[a].w * vb[3].x;
                acc[a][1] += pa[a].x * vb[0].y + pa[a].y * vb[1].y + pa[a].z * vb[2].y + pa[a].w * vb[3].y;
                acc[a][2] += pa[a].x * vb[0].z + pa[a].y * vb[1].z + pa[a].z * vb[2].z + pa[a].w * vb[3].z;
                acc[a][3] += pa[a].x * vb[0].w + pa[a].y * vb[1].w + pa[a].z * vb[2].w + pa[a].w * vb[3].w;
            }
        }
    }

    __syncthreads();

    {
        const int row = tid >> 2, part = tid & 3;
        float dp = 0.f;
        const float* ktr = &Ktail[((size_t)(T0 + row) * NHEAD + h) * 64];
        for (int d = part; d < 64; d += 4) dp += qS[row][d] * ktr[d];
        red[row][part] = dp;
    }
    __syncthreads();
    if (tid < 64) {
        float tl = (red[tid][0] + red[tid][1] + red[tid][2] + red[tid][3]) * 0.125f;
        float mold = mrow[tid];
        float mf = fmaxf(mold, tl);
        float al = __expf(mold - mf);
        float pt = __expf(tl - mf);
        float lf = al * lrow[tid] + pt;
        arow[tid] = al;
        lrow[tid] = pt / lf;
        mrow[tid] = 1.f / lf;
    }
    __syncthreads();

    #pragma unroll
    for (int a = 0; a < 4; ++a) {
        int qq = ty + 16 * a;
        float al_inv = arow[qq] * mrow[qq];
        float ptinv = lrow[qq];
        size_t base = ((size_t)(T0 + qq) * NHEAD + h) * 64 + tx * 4;
        float4 vt = *(const float4*)&Vtail[base];
        float4 o;
        o.x = acc[a][0] * al_inv + ptinv * vt.x;
        o.y = acc[a][1] * al_inv + ptinv * vt.y;
        o.z = acc[a][2] * al_inv + ptinv * vt.z;
        o.w = acc[a][3] * al_inv + ptinv * vt.w;
        *(float4*)&attout[base] = o;
    }
}

extern "C" void kernel_launch(void* const* d_in, const int* in_sizes, int n_in,
                              void* d_out, int out_size, void* d_ws, size_t ws_size,
                              hipStream_t stream)
{
    const float* x   = (const float*)d_in[0];
    const float* Wq  = (const float*)d_in[1];
    const float* Wk  = (const float*)d_in[2];
    const float* Wv  = (const float*)d_in[3];
    const float* Wks = (const float*)d_in[4];
    const float* bks = (const float*)d_in[5];
    const float* Wvs = (const float*)d_in[6];
    const float* bvs = (const float*)d_in[7];
    const float* Wc  = (const float*)d_in[8];
    const float* bc  = (const float*)d_in[9];
    float* out = (float*)d_out;

    float* ws = (float*)d_ws;
    const size_t TC = (size_t)TLEN * CDIM;
    float* q      = ws;
    float* k      = q + TC;
    float* v      = k + TC;
    float* kkv    = v + TC;
    float* vvv    = kkv + TC;
    float* Kt     = vvv + TC;
    float* Vt     = Kt + TC;
    float* Kset   = Vt + TC;
    float* Vset   = Kset + (size_t)NSETS * CDIM;
    float* attout = Vset + (size_t)NSETS * CDIM;
    // W f16 blob (1 MB) aliased onto attout (6 MB): attout written only by attn_tiled,
    // which runs after map_f16's last read of the blob.
    _Float16* Wblob = (_Float16*)attout;

    dim3 gg(CDIM / 64, TLEN / 64);
    gemm64<1, 0><<<gg, 256, 0, stream>>>(x, Wq, nullptr, q, TLEN, CDIM, CDIM);
    gemm64<1, 0><<<gg, 256, 0, stream>>>(x, Wk, nullptr, k, TLEN, CDIM, CDIM);
    gemm64<0, 0><<<gg, 256, 0, stream>>>(x, Wv, nullptr, v, TLEN, CDIM, CDIM);

    prep_w<<<(4096 * 128) / 256, 256, 0, stream>>>(Wks, Wvs, Wblob);

    map_f16<<<(TLEN * NHEAD) / 32, 256, 0, stream>>>(k, v, Wblob, kkv, vvv);

    tail_kernel<<<(TLEN * CDIM) / 256, 256, 0, stream>>>(kkv, vvv, bks, bvs, Kt, Vt);
    set_kernel<<<NSETS * NHEAD, 64, 0, stream>>>(kkv, vvv, bks, bvs, Kset, Vset);

    attn_tiled<<<TLEN / 64 * NHEAD, 256, 0, stream>>>(q, Kset, Vset, Kt, Vt, attout);

    gemm64<0, 1><<<gg, 256, 0, stream>>>(attout, Wc, bc, out, TLEN, CDIM, CDIM);
}

// Round 6
// 563.622 us; speedup vs baseline: 2.9816x; 1.3625x over previous
//
#include <hip/hip_runtime.h>
#include <cstdint>

#define NHEAD 12
#define TLEN 2048
#define CDIM 768
#define NSETS 1023   // 512+256+128+64+32+16+8+4+2+1

typedef __attribute__((ext_vector_type(8))) _Float16 half8;
typedef __attribute__((ext_vector_type(2))) __fp16 fp16x2;
typedef __attribute__((ext_vector_type(4))) float f32x4;

__device__ __forceinline__ float elu1(float x) { return x > 0.f ? x + 1.f : __expf(x); }

// ---------- generic 64x64-tile f32 GEMM: C = A[M,K] @ B[K,N] (+bias) (+elu+1) ----------
template<int ACT, int BIAS>
__global__ __launch_bounds__(256) void gemm64(
    const float* __restrict__ A, const float* __restrict__ B,
    const float* __restrict__ bias, float* __restrict__ Cmat,
    int M, int N, int K)
{
    __shared__ float As[64][17];
    __shared__ float Bs[16][65];
    const int tid = threadIdx.x;
    const int tx = tid & 15, ty = tid >> 4;
    const int m0 = blockIdx.y * 64, n0 = blockIdx.x * 64;
    float acc[4][4] = {};
    for (int k0 = 0; k0 < K; k0 += 16) {
        #pragma unroll
        for (int i = 0; i < 4; ++i) {
            int e = tid + i * 256;
            int ar = e >> 4, ac = e & 15;
            As[ar][ac] = A[(size_t)(m0 + ar) * K + k0 + ac];
            int br = e >> 6, bc = e & 63;
            Bs[br][bc] = B[(size_t)(k0 + br) * N + n0 + bc];
        }
        __syncthreads();
        #pragma unroll
        for (int kk = 0; kk < 16; ++kk) {
            float ra[4], rb[4];
            #pragma unroll
            for (int a = 0; a < 4; ++a) ra[a] = As[ty + a * 16][kk];
            #pragma unroll
            for (int b = 0; b < 4; ++b) rb[b] = Bs[kk][tx + b * 16];
            #pragma unroll
            for (int a = 0; a < 4; ++a)
                #pragma unroll
                for (int b = 0; b < 4; ++b)
                    acc[a][b] += ra[a] * rb[b];
        }
        __syncthreads();
    }
    #pragma unroll
    for (int a = 0; a < 4; ++a) {
        int m = m0 + ty + a * 16;
        #pragma unroll
        for (int b = 0; b < 4; ++b) {
            int n = n0 + tx + b * 16;
            float v = acc[a][b];
            if (BIAS) v += bias[n];
            if (ACT) v = elu1(v);
            Cmat[(size_t)m * N + n] = v;
        }
    }
}

// ---------- prep: W -> f16 fragment-major blob ----------
__global__ __launch_bounds__(256) void prep_w(
    const float* __restrict__ Wks, const float* __restrict__ Wvs,
    _Float16* __restrict__ Wblob)
{
    const int idx = blockIdx.x * 256 + threadIdx.x;   // 4096*128
    const int kk = idx >> 7, n = idx & 127;
    float f = (n < 64) ? Wks[(size_t)kk * 64 + n] : Wvs[(size_t)kk * 64 + (n - 64)];
    const int i = kk >> 6, kl = kk & 63;
    const int ks = kl >> 5, quad = (kl >> 3) & 3, j = kl & 7;
    const int nsg = n >> 4, lane15 = n & 15;
    const int lane = quad * 16 + lane15;
    const size_t off = ((size_t)(((i * 2 + ks) * 8 + nsg)) * 64 + lane) * 8 + j;
    Wblob[off] = (_Float16)f;   // RNE
}

// ---------- MFMA mapped features, f16 exact-split, direct-global B, no K-loop barriers ----
__global__ __launch_bounds__(256, 3) void map_f16(
    const float* __restrict__ kbuf, const float* __restrict__ vbuf,
    const _Float16* __restrict__ Wblob,
    float* __restrict__ kkv, float* __restrict__ vvv)
{
    __shared__ float kS[32][68];

    const int tid = threadIdx.x;
    const int p0 = blockIdx.x * 32;
    const int wave = tid >> 6, lane = tid & 63;
    const int lane15 = lane & 15, quad = lane >> 4;

    #pragma unroll
    for (int u = 0; u < 2; ++u) {
        int c = tid + u * 256;
        int row = c >> 4, col = (c & 15) * 4;
        *(float4*)&kS[row][col] = *(const float4*)&kbuf[(size_t)(p0 + row) * 64 + col];
    }

    float vr[2][2][8];
    #pragma unroll
    for (int ms = 0; ms < 2; ++ms) {
        const size_t pbase = (size_t)(p0 + ms * 16 + lane15) * 64;
        #pragma unroll
        for (int ks = 0; ks < 2; ++ks) {
            *(float4*)&vr[ms][ks][0] = *(const float4*)&vbuf[pbase + ks * 32 + quad * 8];
            *(float4*)&vr[ms][ks][4] = *(const float4*)&vbuf[pbase + ks * 32 + quad * 8 + 4];
        }
    }

    __syncthreads();

    const half8* __restrict__ Wc = (const half8*)Wblob;

    f32x4 acc[2][2];
    #pragma unroll
    for (int ms = 0; ms < 2; ++ms)
        #pragma unroll
        for (int ns = 0; ns < 2; ++ns)
            acc[ms][ns] = (f32x4){0.f, 0.f, 0.f, 0.f};

    half8 bA[4], bB[4];
    float kA[2], kB[2];

    auto loadB = [&](half8* b, int i) {
        #pragma unroll
        for (int ks = 0; ks < 2; ++ks)
            #pragma unroll
            for (int nsl = 0; nsl < 2; ++nsl)
                b[ks * 2 + nsl] = Wc[(size_t)((i * 2 + ks) * 8 + wave * 2 + nsl) * 64 + lane];
    };
    auto loadK = [&](float* kf, int i) {
        kf[0] = kS[lane15][i];
        kf[1] = kS[16 + lane15][i];
    };
    auto compute = [&](const half8* b, const float* kf) {
        #pragma unroll
        for (int ks = 0; ks < 2; ++ks) {
            half8 ah[2], al[2];
            #pragma unroll
            for (int ms = 0; ms < 2; ++ms) {
                union { fp16x2 h2[4]; half8 h8; } uh, ul;
                #pragma unroll
                for (int jp = 0; jp < 4; ++jp) {
                    float pa = kf[ms] * vr[ms][ks][2 * jp];
                    float pb = kf[ms] * vr[ms][ks][2 * jp + 1];
                    fp16x2 hh = __builtin_amdgcn_cvt_pkrtz(pa, pb);
                    uh.h2[jp] = hh;
                    ul.h2[jp] = __builtin_amdgcn_cvt_pkrtz(pa - (float)hh[0], pb - (float)hh[1]);
                }
                ah[ms] = uh.h8; al[ms] = ul.h8;
            }
            #pragma unroll
            for (int nsl = 0; nsl < 2; ++nsl) {
                half8 bb = b[ks * 2 + nsl];
                #pragma unroll
                for (int ms = 0; ms < 2; ++ms) {
                    acc[ms][nsl] = __builtin_amdgcn_mfma_f32_16x16x32_f16(ah[ms], bb, acc[ms][nsl], 0, 0, 0);
                    acc[ms][nsl] = __builtin_amdgcn_mfma_f32_16x16x32_f16(al[ms], bb, acc[ms][nsl], 0, 0, 0);
                }
            }
        }
    };

    loadB(bA, 0); loadK(kA, 0);
    for (int i = 0; i < 64; i += 2) {
        loadB(bB, i + 1); loadK(kB, i + 1);
        compute(bA, kA);
        if (i + 2 < 64) { loadB(bA, i + 2); loadK(kA, i + 2); }
        compute(bB, kB);
    }

    float* dst = (wave >= 2) ? vvv : kkv;
    const int nbase = (wave & 1) * 32;
    #pragma unroll
    for (int ms = 0; ms < 2; ++ms) {
        #pragma unroll
        for (int nsl = 0; nsl < 2; ++nsl) {
            #pragma unroll
            for (int r = 0; r < 4; ++r) {
                int p = p0 + ms * 16 + quad * 4 + r;
                int col = nbase + nsl * 16 + lane15;
                dst[(size_t)p * 64 + col] = acc[ms][nsl][r];
            }
        }
    }
}

// ---------- tail features ----------
__global__ __launch_bounds__(256) void tail_kernel(
    const float* __restrict__ kkv, const float* __restrict__ vvv,
    const float* __restrict__ bks, const float* __restrict__ bvs,
    float* __restrict__ Kt, float* __restrict__ Vt)
{
    const int idx = blockIdx.x * 256 + threadIdx.x;
    const int t = idx / CDIM;
    const int r = idx % CDIM;
    const int d = r & 63;
    const int t0 = t & ~3;
    float ak = bks[d], av = bvs[d];
    for (int tt = t0; tt <= t; ++tt) {
        ak += kkv[(size_t)tt * CDIM + r];
        av += vvv[(size_t)tt * CDIM + r];
    }
    Kt[idx] = ak;
    Vt[idx] = av;
}

// ---------- set features, hierarchical ----------
// set_lower: one block = (head, 128-pos chunk). Levels 2..7 via pairwise LDS tree.
// Raw level-7 sums -> scratch for set_upper.
__global__ __launch_bounds__(256) void set_lower(
    const float* __restrict__ kkv, const float* __restrict__ vvv,
    const float* __restrict__ bks, const float* __restrict__ bvs,
    float* __restrict__ Kset, float* __restrict__ Vset,
    float* __restrict__ scrK, float* __restrict__ scrV)
{
    __shared__ float curK[63][64];   // rows: lv2 0..31, lv3 32..47, lv4 48..55, lv5 56..59, lv6 60..61, lv7 62
    __shared__ float curV[63][64];
    const int tid = threadIdx.x;
    const int col = tid & 63, grp = tid >> 6;
    const int h = blockIdx.x % NHEAD;
    const int c = blockIdx.x / NHEAD;      // 16 chunks
    const int t0 = c * 128;
    const float bk = bks[col], bv = bvs[col];

    // level 2: 32 sets of 4 rows, read kkv/vvv once
    for (int j = grp; j < 32; j += 4) {
        const float* pk = kkv + (size_t)(t0 + j * 4) * CDIM + h * 64 + col;
        const float* pv = vvv + (size_t)(t0 + j * 4) * CDIM + h * 64 + col;
        float sk = pk[0] + pk[CDIM] + pk[2 * CDIM] + pk[3 * CDIM];
        float sv = pv[0] + pv[CDIM] + pv[2 * CDIM] + pv[3 * CDIM];
        curK[j][col] = sk; curV[j][col] = sv;
        size_t o = ((size_t)(c * 32 + j) * NHEAD + h) * 64 + col;
        Kset[o] = sk + bk; Vset[o] = sv + bv;
    }
    __syncthreads();

    const int LBASE[6] = {0, 32, 48, 56, 60, 62};
    const int GBASE[6] = {0, 512, 768, 896, 960, 992};
    #pragma unroll
    for (int li = 1; li < 6; ++li) {
        const int ns = 32 >> li;
        for (int j = grp; j < ns; j += 4) {
            float sk = curK[LBASE[li - 1] + 2 * j][col] + curK[LBASE[li - 1] + 2 * j + 1][col];
            float sv = curV[LBASE[li - 1] + 2 * j][col] + curV[LBASE[li - 1] + 2 * j + 1][col];
            curK[LBASE[li] + j][col] = sk; curV[LBASE[li] + j][col] = sv;
            size_t o = ((size_t)(GBASE[li] + c * ns + j) * NHEAD + h) * 64 + col;
            Kset[o] = sk + bk; Vset[o] = sv + bv;
        }
        __syncthreads();
    }

    if (grp == 0) {
        scrK[((size_t)h * 16 + c) * 64 + col] = curK[62][col];
        scrV[((size_t)h * 16 + c) * 64 + col] = curV[62][col];
    }
}

// set_upper: one block per head; levels 8..11 from the 16 level-7 partials.
__global__ __launch_bounds__(256) void set_upper(
    const float* __restrict__ scrK, const float* __restrict__ scrV,
    const float* __restrict__ bks, const float* __restrict__ bvs,
    float* __restrict__ Kset, float* __restrict__ Vset)
{
    __shared__ float cK[15][64], cV[15][64];   // lv8 0..7, lv9 8..11, lv10 12..13, lv11 14
    const int h = blockIdx.x;
    const int tid = threadIdx.x, col = tid & 63, grp = tid >> 6;
    const float bk = bks[col], bv = bvs[col];

    for (int j = grp; j < 8; j += 4) {
        float sk = scrK[((size_t)h * 16 + 2 * j) * 64 + col] + scrK[((size_t)h * 16 + 2 * j + 1) * 64 + col];
        float sv = scrV[((size_t)h * 16 + 2 * j) * 64 + col] + scrV[((size_t)h * 16 + 2 * j + 1) * 64 + col];
        cK[j][col] = sk; cV[j][col] = sv;
        size_t o = ((size_t)(1008 + j) * NHEAD + h) * 64 + col;
        Kset[o] = sk + bk; Vset[o] = sv + bv;
    }
    __syncthreads();
    const int LB[4] = {0, 8, 12, 14};
    const int GB[4] = {1008, 1016, 1020, 1022};
    #pragma unroll
    for (int li = 1; li < 4; ++li) {
        const int ns = 8 >> li;
        for (int j = grp; j < ns; j += 4) {
            float sk = cK[LB[li - 1] + 2 * j][col] + cK[LB[li - 1] + 2 * j + 1][col];
            float sv = cV[LB[li - 1] + 2 * j][col] + cV[LB[li - 1] + 2 * j + 1][col];
            cK[LB[li] + j][col] = sk; cV[LB[li] + j][col] = sv;
            size_t o = ((size_t)(GB[li] + j) * NHEAD + h) * 64 + col;
            Kset[o] = sk + bk; Vset[o] = sv + bv;
        }
        __syncthreads();
    }
}

// ---------- tiled flash-style attention ----------
__global__ __launch_bounds__(256) void attn_tiled(
    const float* __restrict__ qbuf, const float* __restrict__ Kset,
    const float* __restrict__ Vset, const float* __restrict__ Ktail,
    const float* __restrict__ Vtail, float* __restrict__ attout)
{
    __shared__ float qS[64][68];
    __shared__ float kS[64][68];
    __shared__ float vS[64][68];
    __shared__ float sS[64][68];
    __shared__ float mrow[64], lrow[64], arow[64];
    __shared__ float red[64][4];
    __shared__ int   sid[64];
    __shared__ int   send[64];

    const int tid = threadIdx.x;
    const int b   = blockIdx.x / NHEAD;
    const int h   = blockIdx.x % NHEAD;
    const int T0  = b * 64;
    const int tx  = tid & 15, ty = tid >> 4;

    const int Tend = T0 + 64;
    const int LOFF[10] = {0, 512, 768, 896, 960, 992, 1008, 1016, 1020, 1022};
    int cnt[10], pfx[10], Vtot = 0;
    #pragma unroll
    for (int li = 0; li < 10; ++li) { cnt[li] = Tend >> (li + 2); pfx[li] = Vtot; Vtot += cnt[li]; }

    #pragma unroll
    for (int i = 0; i < 4; ++i) {
        int qi = (tid >> 4) + 16 * i;
        int d4 = tid & 15;
        *(float4*)&qS[qi][d4 * 4] =
            *(const float4*)&qbuf[((size_t)(T0 + qi) * NHEAD + h) * 64 + d4 * 4];
    }
    if (tid < 64) { mrow[tid] = -1e30f; lrow[tid] = 0.f; }

    float acc[4][4] = {};
    const int ntiles = (Vtot + 63) >> 6;

    for (int tile = 0; tile < ntiles; ++tile) {
        __syncthreads();

        if (tid < 64) {
            int j = tile * 64 + tid;
            int s_ = 0, e_ = 0x7fffffff;
            if (j < Vtot) {
                int li = 0;
                #pragma unroll
                for (int u = 1; u < 10; ++u) if (j >= pfx[u]) li = u;
                int idx = j - pfx[li];
                s_ = LOFF[li] + idx;
                e_ = (idx + 1) << (li + 2);
            }
            sid[tid] = s_; send[tid] = e_;
        }
        __syncthreads();

        #pragma unroll
        for (int i = 0; i < 4; ++i) {
            int s  = (tid >> 4) + 16 * i;
            int d4 = tid & 15;
            size_t base = ((size_t)sid[s] * NHEAD + h) * 64 + d4 * 4;
            *(float4*)&kS[s][d4 * 4] = *(const float4*)&Kset[base];
            *(float4*)&vS[s][d4 * 4] = *(const float4*)&Vset[base];
        }
        __syncthreads();

        float lacc[4][4] = {};
        #pragma unroll 4
        for (int d4 = 0; d4 < 16; ++d4) {
            float4 ra[4], rb[4];
            #pragma unroll
            for (int a = 0; a < 4; ++a) ra[a] = *(float4*)&qS[ty + 16 * a][d4 * 4];
            #pragma unroll
            for (int b2 = 0; b2 < 4; ++b2) rb[b2] = *(float4*)&kS[tx + 16 * b2][d4 * 4];
            #pragma unroll
            for (int a = 0; a < 4; ++a)
                #pragma unroll
                for (int b2 = 0; b2 < 4; ++b2)
                    lacc[a][b2] += ra[a].x * rb[b2].x + ra[a].y * rb[b2].y
                                 + ra[a].z * rb[b2].z + ra[a].w * rb[b2].w;
        }
        #pragma unroll
        for (int a = 0; a < 4; ++a) {
            int qq = ty + 16 * a;
            #pragma unroll
            for (int b2 = 0; b2 < 4; ++b2) {
                int s = tx + 16 * b2;
                bool ok = (T0 + qq + 1) >= send[s];
                sS[qq][s] = ok ? lacc[a][b2] * 0.125f : -1e30f;
            }
        }
        __syncthreads();

        const int row = tid >> 2, part = tid & 3;
        float mx = -3e38f;
        for (int s = part; s < 64; s += 4) mx = fmaxf(mx, sS[row][s]);
        red[row][part] = mx;
        __syncthreads();
        if (tid < 64) {
            float rmax = fmaxf(fmaxf(red[tid][0], red[tid][1]), fmaxf(red[tid][2], red[tid][3]));
            float mold = mrow[tid];
            float mnew = fmaxf(mold, rmax);
            arow[tid] = __expf(mold - mnew);
            mrow[tid] = mnew;
        }
        __syncthreads();

        float sum = 0.f;
        const float mn = mrow[row];
        for (int s = part; s < 64; s += 4) {
            float v0 = sS[row][s];
            float p = v0 > -1e29f ? __expf(v0 - mn) : 0.f;
            sS[row][s] = p;
            sum += p;
        }
        red[row][part] = sum;
        __syncthreads();
        if (tid < 64)
            lrow[tid] = arow[tid] * lrow[tid] + red[tid][0] + red[tid][1] + red[tid][2] + red[tid][3];
        #pragma unroll
        for (int a = 0; a < 4; ++a) {
            float al = arow[ty + 16 * a];
            #pragma unroll
            for (int b2 = 0; b2 < 4; ++b2) acc[a][b2] *= al;
        }

        #pragma unroll 4
        for (int s4 = 0; s4 < 16; ++s4) {
            float4 pa[4], vb[4];
            #pragma unroll
            for (int a = 0; a < 4; ++a) pa[a] = *(float4*)&sS[ty + 16 * a][s4 * 4];
            #pragma unroll
            for (int j = 0; j < 4; ++j) vb[j] = *(float4*)&vS[s4 * 4 + j][tx * 4];
            #pragma unroll
            for (int a = 0; a < 4; ++a) {
                acc[a][0] += pa[a].x * vb[0].x + pa[a].y * vb[1].x + pa[a].z * vb[2].x + pa[a].w * vb[3].x;
                acc[a][1] += pa[a].x * vb[0].y + pa[a].y * vb[1].y + pa[a].z * vb[2].y + pa[a].w * vb[3].y;
                acc[a][2] += pa[a].x * vb[0].z + pa[a].y * vb[1].z + pa[a].z * vb[2].z + pa[a].w * vb[3].z;
                acc[a][3] += pa[a].x * vb[0].w + pa[a].y * vb[1].w + pa[a].z * vb[2].w + pa[a].w * vb[3].w;
            }
        }
    }

    __syncthreads();

    {
        const int row = tid >> 2, part = tid & 3;
        float dp = 0.f;
        const float* ktr = &Ktail[((size_t)(T0 + row) * NHEAD + h) * 64];
        for (int d = part; d < 64; d += 4) dp += qS[row][d] * ktr[d];
        red[row][part] = dp;
    }
    __syncthreads();
    if (tid < 64) {
        float tl = (red[tid][0] + red[tid][1] + red[tid][2] + red[tid][3]) * 0.125f;
        float mold = mrow[tid];
        float mf = fmaxf(mold, tl);
        float al = __expf(mold - mf);
        float pt = __expf(tl - mf);
        float lf = al * lrow[tid] + pt;
        arow[tid] = al;
        lrow[tid] = pt / lf;
        mrow[tid] = 1.f / lf;
    }
    __syncthreads();

    #pragma unroll
    for (int a = 0; a < 4; ++a) {
        int qq = ty + 16 * a;
        float al_inv = arow[qq] * mrow[qq];
        float ptinv = lrow[qq];
        size_t base = ((size_t)(T0 + qq) * NHEAD + h) * 64 + tx * 4;
        float4 vt = *(const float4*)&Vtail[base];
        float4 o;
        o.x = acc[a][0] * al_inv + ptinv * vt.x;
        o.y = acc[a][1] * al_inv + ptinv * vt.y;
        o.z = acc[a][2] * al_inv + ptinv * vt.z;
        o.w = acc[a][3] * al_inv + ptinv * vt.w;
        *(float4*)&attout[base] = o;
    }
}

extern "C" void kernel_launch(void* const* d_in, const int* in_sizes, int n_in,
                              void* d_out, int out_size, void* d_ws, size_t ws_size,
                              hipStream_t stream)
{
    const float* x   = (const float*)d_in[0];
    const float* Wq  = (const float*)d_in[1];
    const float* Wk  = (const float*)d_in[2];
    const float* Wv  = (const float*)d_in[3];
    const float* Wks = (const float*)d_in[4];
    const float* bks = (const float*)d_in[5];
    const float* Wvs = (const float*)d_in[6];
    const float* bvs = (const float*)d_in[7];
    const float* Wc  = (const float*)d_in[8];
    const float* bc  = (const float*)d_in[9];
    float* out = (float*)d_out;

    float* ws = (float*)d_ws;
    const size_t TC = (size_t)TLEN * CDIM;
    float* q      = ws;
    float* k      = q + TC;
    float* v      = k + TC;
    float* kkv    = v + TC;
    float* vvv    = kkv + TC;
    float* Kt     = vvv + TC;
    float* Vt     = Kt + TC;
    float* Kset   = Vt + TC;
    float* Vset   = Kset + (size_t)NSETS * CDIM;
    float* attout = Vset + (size_t)NSETS * CDIM;
    // Aliases into attout (dead until attn_tiled writes it, which runs after all readers):
    //   Wblob: first 262144 floats (f16 blob, read by map_f16)
    //   scrK/scrV: level-7 partials (written by set_lower, read by set_upper)
    _Float16* Wblob = (_Float16*)attout;
    float* scrK = attout + (1 << 20);
    float* scrV = scrK + 12 * 16 * 64;

    dim3 gg(CDIM / 64, TLEN / 64);
    gemm64<1, 0><<<gg, 256, 0, stream>>>(x, Wq, nullptr, q, TLEN, CDIM, CDIM);
    gemm64<1, 0><<<gg, 256, 0, stream>>>(x, Wk, nullptr, k, TLEN, CDIM, CDIM);
    gemm64<0, 0><<<gg, 256, 0, stream>>>(x, Wv, nullptr, v, TLEN, CDIM, CDIM);

    prep_w<<<(4096 * 128) / 256, 256, 0, stream>>>(Wks, Wvs, Wblob);

    map_f16<<<(TLEN * NHEAD) / 32, 256, 0, stream>>>(k, v, Wblob, kkv, vvv);

    tail_kernel<<<(TLEN * CDIM) / 256, 256, 0, stream>>>(kkv, vvv, bks, bvs, Kt, Vt);

    set_lower<<<16 * NHEAD, 256, 0, stream>>>(kkv, vvv, bks, bvs, Kset, Vset, scrK, scrV);
    set_upper<<<NHEAD, 256, 0, stream>>>(scrK, scrV, bks, bvs, Kset, Vset);

    attn_tiled<<<TLEN / 64 * NHEAD, 256, 0, stream>>>(q, Kset, Vset, Kt, Vt, attout);

    gemm64<0, 1><<<gg, 256, 0, stream>>>(attout, Wc, bc, out, TLEN, CDIM, CDIM);
}

// Round 7
// 481.589 us; speedup vs baseline: 3.4895x; 1.1703x over previous
//
#include <hip/hip_runtime.h>
#include <cstdint>

#define NHEAD 12
#define TLEN 2048
#define CDIM 768
#define NSETS 1023   // 512+256+128+64+32+16+8+4+2+1

typedef __attribute__((ext_vector_type(8))) _Float16 half8;
typedef __attribute__((ext_vector_type(2))) __fp16 fp16x2;
typedef __attribute__((ext_vector_type(8))) short short8;   // 8 bf16
typedef __attribute__((ext_vector_type(4))) float f32x4;

__device__ __forceinline__ float elu1(float x) { return x > 0.f ? x + 1.f : __expf(x); }

// pack truncated-bf16 of two floats: low half = bf16(a), high half = bf16(b)
__device__ __forceinline__ unsigned pack2_bf16_trunc(float a, float b) {
    unsigned ua = __float_as_uint(a), ub = __float_as_uint(b);
    return __builtin_amdgcn_perm(ub, ua, 0x07060302);
}
// RNE bf16 pack
__device__ __forceinline__ unsigned pack2_bf16_rne(float a, float b) {
    unsigned ua = __float_as_uint(a), ub = __float_as_uint(b);
    ua = ua + 0x7fff + ((ua >> 16) & 1);
    ub = ub + 0x7fff + ((ub >> 16) & 1);
    return (ub & 0xffff0000u) | (ua >> 16);
}
__device__ __forceinline__ short8 mk_short8(const unsigned* u) {
    union { unsigned w[4]; short8 s; } x;
    x.w[0] = u[0]; x.w[1] = u[1]; x.w[2] = u[2]; x.w[3] = u[3];
    return x.s;
}
// split 8 f32 into exact bf16 hi + residual-bf16 lo fragments
__device__ __forceinline__ void split8_bf16(const float* f, short8& hi, short8& lo) {
    unsigned hp[4], lp[4];
    #pragma unroll
    for (int p = 0; p < 4; ++p) {
        float a = f[2 * p], b = f[2 * p + 1];
        unsigned ua = __float_as_uint(a), ub = __float_as_uint(b);
        hp[p] = __builtin_amdgcn_perm(ub, ua, 0x07060302);
        float ra = a - __uint_as_float(ua & 0xffff0000u);
        float rb = b - __uint_as_float(ub & 0xffff0000u);
        lp[p] = pack2_bf16_trunc(ra, rb);
    }
    hi = mk_short8(hp); lo = mk_short8(lp);
}

// ---------- generic 64x64-tile f32 GEMM: C = A[M,K] @ B[K,N] (+bias) (+elu+1) ----------
template<int ACT, int BIAS>
__global__ __launch_bounds__(256) void gemm64(
    const float* __restrict__ A, const float* __restrict__ B,
    const float* __restrict__ bias, float* __restrict__ Cmat,
    int M, int N, int K)
{
    __shared__ float As[64][17];
    __shared__ float Bs[16][65];
    const int tid = threadIdx.x;
    const int tx = tid & 15, ty = tid >> 4;
    const int m0 = blockIdx.y * 64, n0 = blockIdx.x * 64;
    float acc[4][4] = {};
    for (int k0 = 0; k0 < K; k0 += 16) {
        #pragma unroll
        for (int i = 0; i < 4; ++i) {
            int e = tid + i * 256;
            int ar = e >> 4, ac = e & 15;
            As[ar][ac] = A[(size_t)(m0 + ar) * K + k0 + ac];
            int br = e >> 6, bc = e & 63;
            Bs[br][bc] = B[(size_t)(k0 + br) * N + n0 + bc];
        }
        __syncthreads();
        #pragma unroll
        for (int kk = 0; kk < 16; ++kk) {
            float ra[4], rb[4];
            #pragma unroll
            for (int a = 0; a < 4; ++a) ra[a] = As[ty + a * 16][kk];
            #pragma unroll
            for (int b = 0; b < 4; ++b) rb[b] = Bs[kk][tx + b * 16];
            #pragma unroll
            for (int a = 0; a < 4; ++a)
                #pragma unroll
                for (int b = 0; b < 4; ++b)
                    acc[a][b] += ra[a] * rb[b];
        }
        __syncthreads();
    }
    #pragma unroll
    for (int a = 0; a < 4; ++a) {
        int m = m0 + ty + a * 16;
        #pragma unroll
        for (int b = 0; b < 4; ++b) {
            int n = n0 + tx + b * 16;
            float v = acc[a][b];
            if (BIAS) v += bias[n];
            if (ACT) v = elu1(v);
            Cmat[(size_t)m * N + n] = v;
        }
    }
}

// ---------- prep: W -> f16 fragment-major blob ----------
__global__ __launch_bounds__(256) void prep_w(
    const float* __restrict__ Wks, const float* __restrict__ Wvs,
    _Float16* __restrict__ Wblob)
{
    const int idx = blockIdx.x * 256 + threadIdx.x;   // 4096*128
    const int kk = idx >> 7, n = idx & 127;
    float f = (n < 64) ? Wks[(size_t)kk * 64 + n] : Wvs[(size_t)kk * 64 + (n - 64)];
    const int i = kk >> 6, kl = kk & 63;
    const int ks = kl >> 5, quad = (kl >> 3) & 3, j = kl & 7;
    const int nsg = n >> 4, lane15 = n & 15;
    const int lane = quad * 16 + lane15;
    const size_t off = ((size_t)(((i * 2 + ks) * 8 + nsg)) * 64 + lane) * 8 + j;
    Wblob[off] = (_Float16)f;   // RNE
}

// ---------- MFMA mapped features, f16 exact-split, direct-global B ----------
__global__ __launch_bounds__(256, 3) void map_f16(
    const float* __restrict__ kbuf, const float* __restrict__ vbuf,
    const _Float16* __restrict__ Wblob,
    float* __restrict__ kkv, float* __restrict__ vvv)
{
    __shared__ float kS[32][68];

    const int tid = threadIdx.x;
    const int p0 = blockIdx.x * 32;
    const int wave = tid >> 6, lane = tid & 63;
    const int lane15 = lane & 15, quad = lane >> 4;

    #pragma unroll
    for (int u = 0; u < 2; ++u) {
        int c = tid + u * 256;
        int row = c >> 4, col = (c & 15) * 4;
        *(float4*)&kS[row][col] = *(const float4*)&kbuf[(size_t)(p0 + row) * 64 + col];
    }

    float vr[2][2][8];
    #pragma unroll
    for (int ms = 0; ms < 2; ++ms) {
        const size_t pbase = (size_t)(p0 + ms * 16 + lane15) * 64;
        #pragma unroll
        for (int ks = 0; ks < 2; ++ks) {
            *(float4*)&vr[ms][ks][0] = *(const float4*)&vbuf[pbase + ks * 32 + quad * 8];
            *(float4*)&vr[ms][ks][4] = *(const float4*)&vbuf[pbase + ks * 32 + quad * 8 + 4];
        }
    }

    __syncthreads();

    const half8* __restrict__ Wc = (const half8*)Wblob;

    f32x4 acc[2][2];
    #pragma unroll
    for (int ms = 0; ms < 2; ++ms)
        #pragma unroll
        for (int ns = 0; ns < 2; ++ns)
            acc[ms][ns] = (f32x4){0.f, 0.f, 0.f, 0.f};

    half8 bA[4], bB[4];
    float kA[2], kB[2];

    auto loadB = [&](half8* b, int i) {
        #pragma unroll
        for (int ks = 0; ks < 2; ++ks)
            #pragma unroll
            for (int nsl = 0; nsl < 2; ++nsl)
                b[ks * 2 + nsl] = Wc[(size_t)((i * 2 + ks) * 8 + wave * 2 + nsl) * 64 + lane];
    };
    auto loadK = [&](float* kf, int i) {
        kf[0] = kS[lane15][i];
        kf[1] = kS[16 + lane15][i];
    };
    auto compute = [&](const half8* b, const float* kf) {
        #pragma unroll
        for (int ks = 0; ks < 2; ++ks) {
            half8 ah[2], al[2];
            #pragma unroll
            for (int ms = 0; ms < 2; ++ms) {
                union { fp16x2 h2[4]; half8 h8; } uh, ul;
                #pragma unroll
                for (int jp = 0; jp < 4; ++jp) {
                    float pa = kf[ms] * vr[ms][ks][2 * jp];
                    float pb = kf[ms] * vr[ms][ks][2 * jp + 1];
                    fp16x2 hh = __builtin_amdgcn_cvt_pkrtz(pa, pb);
                    uh.h2[jp] = hh;
                    ul.h2[jp] = __builtin_amdgcn_cvt_pkrtz(pa - (float)hh[0], pb - (float)hh[1]);
                }
                ah[ms] = uh.h8; al[ms] = ul.h8;
            }
            #pragma unroll
            for (int nsl = 0; nsl < 2; ++nsl) {
                half8 bb = b[ks * 2 + nsl];
                #pragma unroll
                for (int ms = 0; ms < 2; ++ms) {
                    acc[ms][nsl] = __builtin_amdgcn_mfma_f32_16x16x32_f16(ah[ms], bb, acc[ms][nsl], 0, 0, 0);
                    acc[ms][nsl] = __builtin_amdgcn_mfma_f32_16x16x32_f16(al[ms], bb, acc[ms][nsl], 0, 0, 0);
                }
            }
        }
    };

    loadB(bA, 0); loadK(kA, 0);
    for (int i = 0; i < 64; i += 2) {
        loadB(bB, i + 1); loadK(kB, i + 1);
        compute(bA, kA);
        if (i + 2 < 64) { loadB(bA, i + 2); loadK(kA, i + 2); }
        compute(bB, kB);
    }

    float* dst = (wave >= 2) ? vvv : kkv;
    const int nbase = (wave & 1) * 32;
    #pragma unroll
    for (int ms = 0; ms < 2; ++ms) {
        #pragma unroll
        for (int nsl = 0; nsl < 2; ++nsl) {
            #pragma unroll
            for (int r = 0; r < 4; ++r) {
                int p = p0 + ms * 16 + quad * 4 + r;
                int col = nbase + nsl * 16 + lane15;
                dst[(size_t)p * 64 + col] = acc[ms][nsl][r];
            }
        }
    }
}

// ---------- tail features ----------
__global__ __launch_bounds__(256) void tail_kernel(
    const float* __restrict__ kkv, const float* __restrict__ vvv,
    const float* __restrict__ bks, const float* __restrict__ bvs,
    float* __restrict__ Kt, float* __restrict__ Vt)
{
    const int idx = blockIdx.x * 256 + threadIdx.x;
    const int t = idx / CDIM;
    const int r = idx % CDIM;
    const int d = r & 63;
    const int t0 = t & ~3;
    float ak = bks[d], av = bvs[d];
    for (int tt = t0; tt <= t; ++tt) {
        ak += kkv[(size_t)tt * CDIM + r];
        av += vvv[(size_t)tt * CDIM + r];
    }
    Kt[idx] = ak;
    Vt[idx] = av;
}

// ---------- set features, hierarchical ----------
__global__ __launch_bounds__(256) void set_lower(
    const float* __restrict__ kkv, const float* __restrict__ vvv,
    const float* __restrict__ bks, const float* __restrict__ bvs,
    float* __restrict__ Kset, float* __restrict__ Vset,
    float* __restrict__ scrK, float* __restrict__ scrV)
{
    __shared__ float curK[63][64];
    __shared__ float curV[63][64];
    const int tid = threadIdx.x;
    const int col = tid & 63, grp = tid >> 6;
    const int h = blockIdx.x % NHEAD;
    const int c = blockIdx.x / NHEAD;
    const int t0 = c * 128;
    const float bk = bks[col], bv = bvs[col];

    for (int j = grp; j < 32; j += 4) {
        const float* pk = kkv + (size_t)(t0 + j * 4) * CDIM + h * 64 + col;
        const float* pv = vvv + (size_t)(t0 + j * 4) * CDIM + h * 64 + col;
        float sk = pk[0] + pk[CDIM] + pk[2 * CDIM] + pk[3 * CDIM];
        float sv = pv[0] + pv[CDIM] + pv[2 * CDIM] + pv[3 * CDIM];
        curK[j][col] = sk; curV[j][col] = sv;
        size_t o = ((size_t)(c * 32 + j) * NHEAD + h) * 64 + col;
        Kset[o] = sk + bk; Vset[o] = sv + bv;
    }
    __syncthreads();

    const int LBASE[6] = {0, 32, 48, 56, 60, 62};
    const int GBASE[6] = {0, 512, 768, 896, 960, 992};
    #pragma unroll
    for (int li = 1; li < 6; ++li) {
        const int ns = 32 >> li;
        for (int j = grp; j < ns; j += 4) {
            float sk = curK[LBASE[li - 1] + 2 * j][col] + curK[LBASE[li - 1] + 2 * j + 1][col];
            float sv = curV[LBASE[li - 1] + 2 * j][col] + curV[LBASE[li - 1] + 2 * j + 1][col];
            curK[LBASE[li] + j][col] = sk; curV[LBASE[li] + j][col] = sv;
            size_t o = ((size_t)(GBASE[li] + c * ns + j) * NHEAD + h) * 64 + col;
            Kset[o] = sk + bk; Vset[o] = sv + bv;
        }
        __syncthreads();
    }

    if (grp == 0) {
        scrK[((size_t)h * 16 + c) * 64 + col] = curK[62][col];
        scrV[((size_t)h * 16 + c) * 64 + col] = curV[62][col];
    }
}

__global__ __launch_bounds__(256) void set_upper(
    const float* __restrict__ scrK, const float* __restrict__ scrV,
    const float* __restrict__ bks, const float* __restrict__ bvs,
    float* __restrict__ Kset, float* __restrict__ Vset)
{
    __shared__ float cK[15][64], cV[15][64];
    const int h = blockIdx.x;
    const int tid = threadIdx.x, col = tid & 63, grp = tid >> 6;
    const float bk = bks[col], bv = bvs[col];

    for (int j = grp; j < 8; j += 4) {
        float sk = scrK[((size_t)h * 16 + 2 * j) * 64 + col] + scrK[((size_t)h * 16 + 2 * j + 1) * 64 + col];
        float sv = scrV[((size_t)h * 16 + 2 * j) * 64 + col] + scrV[((size_t)h * 16 + 2 * j + 1) * 64 + col];
        cK[j][col] = sk; cV[j][col] = sv;
        size_t o = ((size_t)(1008 + j) * NHEAD + h) * 64 + col;
        Kset[o] = sk + bk; Vset[o] = sv + bv;
    }
    __syncthreads();
    const int LB[4] = {0, 8, 12, 14};
    const int GB[4] = {1008, 1016, 1020, 1022};
    #pragma unroll
    for (int li = 1; li < 4; ++li) {
        const int ns = 8 >> li;
        for (int j = grp; j < ns; j += 4) {
            float sk = cK[LB[li - 1] + 2 * j][col] + cK[LB[li - 1] + 2 * j + 1][col];
            float sv = cV[LB[li - 1] + 2 * j][col] + cV[LB[li - 1] + 2 * j + 1][col];
            cK[LB[li] + j][col] = sk; cV[LB[li] + j][col] = sv;
            size_t o = ((size_t)(GB[li] + j) * NHEAD + h) * 64 + col;
            Kset[o] = sk + bk; Vset[o] = sv + bv;
        }
        __syncthreads();
    }
}

// ---------- MFMA flash attention: 32 queries/block, QK split-bf16 3-MFMA, PV bf16 ----------
__global__ __launch_bounds__(256, 3) void attn_mfma(
    const float* __restrict__ qbuf, const float* __restrict__ Kset,
    const float* __restrict__ Vset, const float* __restrict__ Ktail,
    const float* __restrict__ Vtail, float* __restrict__ attout)
{
    __shared__ float vS[64][66];
    __shared__ float sS[32][68];
    __shared__ float mrow[32], lrow[32], arow[32];
    __shared__ float red[32][8];
    __shared__ int   sid[64], send[64];

    const int tid = threadIdx.x;
    const int b   = 63 - (blockIdx.x / NHEAD);   // heavy blocks dispatched first
    const int h   = blockIdx.x % NHEAD;
    const int T0  = b * 32;
    const int wave = tid >> 6, lane = tid & 63;
    const int lane15 = lane & 15, quad = lane >> 4;

    const int Tend = T0 + 32;
    const int LOFF[10] = {0, 512, 768, 896, 960, 992, 1008, 1016, 1020, 1022};
    int pfx[10], Vtot = 0;
    #pragma unroll
    for (int li = 0; li < 10; ++li) { pfx[li] = Vtot; Vtot += Tend >> (li + 2); }

    // Q A-fragments, exact bf16 hi/lo split (held all block)
    short8 Qhi[2][2], Qlo[2][2];
    #pragma unroll
    for (int ms = 0; ms < 2; ++ms)
        #pragma unroll
        for (int kt = 0; kt < 2; ++kt) {
            const float* qp = qbuf + ((size_t)(T0 + ms * 16 + lane15) * NHEAD + h) * 64 + kt * 32 + quad * 8;
            float f[8];
            *(float4*)&f[0] = *(const float4*)qp;
            *(float4*)&f[4] = *(const float4*)(qp + 4);
            split8_bf16(f, Qhi[ms][kt], Qlo[ms][kt]);
        }

    if (tid < 32) { mrow[tid] = -1e30f; lrow[tid] = 0.f; }

    f32x4 oacc[2];
    oacc[0] = (f32x4){0.f, 0.f, 0.f, 0.f};
    oacc[1] = (f32x4){0.f, 0.f, 0.f, 0.f};

    const int ntiles = (Vtot + 63) >> 6;
    const int row = tid >> 3, part = tid & 7;

    for (int tile = 0; tile < ntiles; ++tile) {
        __syncthreads();   // protect sid/send/vS from previous-tile readers (+init on tile 0)

        if (tid < 64) {
            int j = tile * 64 + tid;
            int s_ = 0, e_ = 0x7fffffff;
            if (j < Vtot) {
                int li = 0;
                #pragma unroll
                for (int u = 1; u < 10; ++u) if (j >= pfx[u]) li = u;
                int idx = j - pfx[li];
                s_ = LOFF[li] + idx;
                e_ = (idx + 1) << (li + 2);
            }
            sid[tid] = s_; send[tid] = e_;
        }
        __syncthreads();

        // stage V tile rows (f32, coalesced)
        #pragma unroll
        for (int i = 0; i < 4; ++i) {
            int s  = (tid >> 4) + 16 * i;
            int d4 = tid & 15;
            *(float4*)&vS[s][d4 * 4] =
                *(const float4*)&Vset[((size_t)sid[s] * NHEAD + h) * 64 + d4 * 4];
        }

        // K B-fragments direct from global (this wave's 16-set slice), split hi/lo
        short8 Khi[2], Klo[2];
        {
            const int sK = sid[wave * 16 + lane15];
            const float* kp = Kset + ((size_t)sK * NHEAD + h) * 64 + quad * 8;
            #pragma unroll
            for (int kt = 0; kt < 2; ++kt) {
                float f[8];
                *(float4*)&f[0] = *(const float4*)(kp + kt * 32);
                *(float4*)&f[4] = *(const float4*)(kp + kt * 32 + 4);
                split8_bf16(f, Khi[kt], Klo[kt]);
            }
        }

        // QK^T: 3-term split
        f32x4 lacc[2];
        lacc[0] = (f32x4){0.f, 0.f, 0.f, 0.f};
        lacc[1] = (f32x4){0.f, 0.f, 0.f, 0.f};
        #pragma unroll
        for (int kt = 0; kt < 2; ++kt)
            #pragma unroll
            for (int ms = 0; ms < 2; ++ms) {
                lacc[ms] = __builtin_amdgcn_mfma_f32_16x16x32_bf16(Qhi[ms][kt], Khi[kt], lacc[ms], 0, 0, 0);
                lacc[ms] = __builtin_amdgcn_mfma_f32_16x16x32_bf16(Qlo[ms][kt], Khi[kt], lacc[ms], 0, 0, 0);
                lacc[ms] = __builtin_amdgcn_mfma_f32_16x16x32_bf16(Qhi[ms][kt], Klo[kt], lacc[ms], 0, 0, 0);
            }

        // mask + scale, write scores to sS (C layout: row=quad*4+r, col=lane15 within slice)
        {
            const int sendv = send[wave * 16 + lane15];
            #pragma unroll
            for (int ms = 0; ms < 2; ++ms)
                #pragma unroll
                for (int r = 0; r < 4; ++r) {
                    int qrow = ms * 16 + quad * 4 + r;
                    bool ok = (T0 + qrow + 1) >= sendv;
                    sS[qrow][wave * 16 + lane15] = ok ? lacc[ms][r] * 0.125f : -1e30f;
                }
        }
        __syncthreads();

        // softmax pass 1: rowmax
        float mx = -3e38f;
        for (int s = part; s < 64; s += 8) mx = fmaxf(mx, sS[row][s]);
        red[row][part] = mx;
        __syncthreads();
        if (tid < 32) {
            float rmax = red[tid][0];
            #pragma unroll
            for (int u = 1; u < 8; ++u) rmax = fmaxf(rmax, red[tid][u]);
            float mold = mrow[tid];
            float mnew = fmaxf(mold, rmax);
            arow[tid] = __expf(mold - mnew);
            mrow[tid] = mnew;
        }
        __syncthreads();

        // pass 2: exp + rowsum (P stored f32 in sS)
        float sum = 0.f;
        const float mn = mrow[row];
        for (int s = part; s < 64; s += 8) {
            float v0 = sS[row][s];
            float p = v0 > -1e29f ? __expf(v0 - mn) : 0.f;
            sS[row][s] = p;
            sum += p;
        }
        red[row][part] = sum;
        __syncthreads();
        if (tid < 32) {
            float t = 0.f;
            #pragma unroll
            for (int u = 0; u < 8; ++u) t += red[tid][u];
            lrow[tid] = arow[tid] * lrow[tid] + t;
        }

        // rescale O accumulator
        #pragma unroll
        for (int ms = 0; ms < 2; ++ms)
            #pragma unroll
            for (int r = 0; r < 4; ++r)
                oacc[ms][r] *= arow[ms * 16 + quad * 4 + r];
        __syncthreads();   // P fully written before A-frag reads

        // PV: A = P (bf16 RNE), B = V (bf16 RNE), this wave's 16-dim slice
        #pragma unroll
        for (int kt = 0; kt < 2; ++kt) {
            short8 Pf[2];
            #pragma unroll
            for (int ms = 0; ms < 2; ++ms) {
                const float* pp = &sS[ms * 16 + lane15][kt * 32 + quad * 8];
                float f[8];
                *(float4*)&f[0] = *(const float4*)pp;
                *(float4*)&f[4] = *(const float4*)(pp + 4);
                unsigned w[4];
                #pragma unroll
                for (int p = 0; p < 4; ++p) w[p] = pack2_bf16_rne(f[2 * p], f[2 * p + 1]);
                Pf[ms] = mk_short8(w);
            }
            unsigned vw[4];
            #pragma unroll
            for (int jp = 0; jp < 4; ++jp) {
                float a = vS[kt * 32 + quad * 8 + 2 * jp][wave * 16 + lane15];
                float bb = vS[kt * 32 + quad * 8 + 2 * jp + 1][wave * 16 + lane15];
                vw[jp] = pack2_bf16_rne(a, bb);
            }
            short8 Vf = mk_short8(vw);
            #pragma unroll
            for (int ms = 0; ms < 2; ++ms)
                oacc[ms] = __builtin_amdgcn_mfma_f32_16x16x32_bf16(Pf[ms], Vf, oacc[ms], 0, 0, 0);
        }
    }

    __syncthreads();

    // tail column logit
    {
        const float* qr = qbuf  + ((size_t)(T0 + row) * NHEAD + h) * 64;
        const float* kr = Ktail + ((size_t)(T0 + row) * NHEAD + h) * 64;
        float dp = 0.f;
        for (int d = part; d < 64; d += 8) dp += qr[d] * kr[d];
        red[row][part] = dp;
    }
    __syncthreads();
    if (tid < 32) {
        float tl = 0.f;
        #pragma unroll
        for (int u = 0; u < 8; ++u) tl += red[tid][u];
        tl *= 0.125f;
        float mold = mrow[tid];
        float mf = fmaxf(mold, tl);
        float al = __expf(mold - mf);
        float pt = __expf(tl - mf);
        float lf = al * lrow[tid] + pt;
        arow[tid] = al;
        lrow[tid] = pt / lf;    // pt * inv
        mrow[tid] = 1.f / lf;   // inv
    }
    __syncthreads();

    // epilogue: C layout rows quad*4+r, col = wave slice
    #pragma unroll
    for (int ms = 0; ms < 2; ++ms)
        #pragma unroll
        for (int r = 0; r < 4; ++r) {
            int qrow = ms * 16 + quad * 4 + r;
            int col = wave * 16 + lane15;
            float al_inv = arow[qrow] * mrow[qrow];
            float ptinv = lrow[qrow];
            size_t base = ((size_t)(T0 + qrow) * NHEAD + h) * 64 + col;
            attout[base] = oacc[ms][r] * al_inv + ptinv * Vtail[base];
        }
}

extern "C" void kernel_launch(void* const* d_in, const int* in_sizes, int n_in,
                              void* d_out, int out_size, void* d_ws, size_t ws_size,
                              hipStream_t stream)
{
    const float* x   = (const float*)d_in[0];
    const float* Wq  = (const float*)d_in[1];
    const float* Wk  = (const float*)d_in[2];
    const float* Wv  = (const float*)d_in[3];
    const float* Wks = (const float*)d_in[4];
    const float* bks = (const float*)d_in[5];
    const float* Wvs = (const float*)d_in[6];
    const float* bvs = (const float*)d_in[7];
    const float* Wc  = (const float*)d_in[8];
    const float* bc  = (const float*)d_in[9];
    float* out = (float*)d_out;

    float* ws = (float*)d_ws;
    const size_t TC = (size_t)TLEN * CDIM;
    float* q      = ws;
    float* k      = q + TC;
    float* v      = k + TC;
    float* kkv    = v + TC;
    float* vvv    = kkv + TC;
    float* Kt     = vvv + TC;
    float* Vt     = Kt + TC;
    float* Kset   = Vt + TC;
    float* Vset   = Kset + (size_t)NSETS * CDIM;
    float* attout = Vset + (size_t)NSETS * CDIM;
    _Float16* Wblob = (_Float16*)attout;            // dead before attn writes attout
    float* scrK = attout + (1 << 20);
    float* scrV = scrK + 12 * 16 * 64;

    dim3 gg(CDIM / 64, TLEN / 64);
    gemm64<1, 0><<<gg, 256, 0, stream>>>(x, Wq, nullptr, q, TLEN, CDIM, CDIM);
    gemm64<1, 0><<<gg, 256, 0, stream>>>(x, Wk, nullptr, k, TLEN, CDIM, CDIM);
    gemm64<0, 0><<<gg, 256, 0, stream>>>(x, Wv, nullptr, v, TLEN, CDIM, CDIM);

    prep_w<<<(4096 * 128) / 256, 256, 0, stream>>>(Wks, Wvs, Wblob);

    map_f16<<<(TLEN * NHEAD) / 32, 256, 0, stream>>>(k, v, Wblob, kkv, vvv);

    tail_kernel<<<(TLEN * CDIM) / 256, 256, 0, stream>>>(kkv, vvv, bks, bvs, Kt, Vt);

    set_lower<<<16 * NHEAD, 256, 0, stream>>>(kkv, vvv, bks, bvs, Kset, Vset, scrK, scrV);
    set_upper<<<NHEAD, 256, 0, stream>>>(scrK, scrV, bks, bvs, Kset, Vset);

    attn_mfma<<<(TLEN / 32) * NHEAD, 256, 0, stream>>>(q, Kset, Vset, Kt, Vt, attout);

    gemm64<0, 1><<<gg, 256, 0, stream>>>(attout, Wc, bc, out, TLEN, CDIM, CDIM);
}

// Round 8
// 339.706 us; speedup vs baseline: 4.9469x; 1.4177x over previous
//
#include <hip/hip_runtime.h>
#include <cstdint>

#define NHEAD 12
#define TLEN 2048
#define CDIM 768
#define NSETS 1023   // 512+256+128+64+32+16+8+4+2+1

typedef __attribute__((ext_vector_type(8))) _Float16 half8;
typedef __attribute__((ext_vector_type(2))) __fp16 fp16x2;
typedef __attribute__((ext_vector_type(8))) short short8;   // 8 bf16
typedef __attribute__((ext_vector_type(4))) float f32x4;

__device__ __forceinline__ float elu1(float x) { return x > 0.f ? x + 1.f : __expf(x); }

// pack truncated-bf16 of two floats: low half = bf16(a), high half = bf16(b)
__device__ __forceinline__ unsigned pack2_bf16_trunc(float a, float b) {
    unsigned ua = __float_as_uint(a), ub = __float_as_uint(b);
    return __builtin_amdgcn_perm(ub, ua, 0x07060302);
}
// RNE bf16 pack
__device__ __forceinline__ unsigned pack2_bf16_rne(float a, float b) {
    unsigned ua = __float_as_uint(a), ub = __float_as_uint(b);
    ua = ua + 0x7fff + ((ua >> 16) & 1);
    ub = ub + 0x7fff + ((ub >> 16) & 1);
    return (ub & 0xffff0000u) | (ua >> 16);
}
__device__ __forceinline__ short8 mk_short8(const unsigned* u) {
    union { unsigned w[4]; short8 s; } x;
    x.w[0] = u[0]; x.w[1] = u[1]; x.w[2] = u[2]; x.w[3] = u[3];
    return x.s;
}
// split 8 f32 into exact bf16 hi + residual-bf16 lo fragments
__device__ __forceinline__ void split8_bf16(const float* f, short8& hi, short8& lo) {
    unsigned hp[4], lp[4];
    #pragma unroll
    for (int p = 0; p < 4; ++p) {
        float a = f[2 * p], b = f[2 * p + 1];
        unsigned ua = __float_as_uint(a), ub = __float_as_uint(b);
        hp[p] = __builtin_amdgcn_perm(ub, ua, 0x07060302);
        float ra = a - __uint_as_float(ua & 0xffff0000u);
        float rb = b - __uint_as_float(ub & 0xffff0000u);
        lp[p] = pack2_bf16_trunc(ra, rb);
    }
    hi = mk_short8(hp); lo = mk_short8(lp);
}
// split 8 f32 into f16 hi + residual f16 lo
__device__ __forceinline__ void split8_f16(const float* f, half8& hi, half8& lo) {
    union { fp16x2 h2[4]; half8 h8; } uh, ul;
    #pragma unroll
    for (int jp = 0; jp < 4; ++jp) {
        float a = f[2 * jp], b = f[2 * jp + 1];
        fp16x2 hh = __builtin_amdgcn_cvt_pkrtz(a, b);
        uh.h2[jp] = hh;
        ul.h2[jp] = __builtin_amdgcn_cvt_pkrtz(a - (float)hh[0], b - (float)hh[1]);
    }
    hi = uh.h8; lo = ul.h8;
}

// ---------- prep: 768x768 W -> f16 fragment-major blob ----------
// frag chunk (i=k32 idx 0..23, nsg 0..47): halfs at ((i*48+nsg)*64 + lane)*8 + j
// element = W[k = i*32 + quad*8 + j][n = nsg*16 + lane15], lane = quad*16 + lane15
__global__ __launch_bounds__(256) void prep_w768(
    const float* __restrict__ W, _Float16* __restrict__ blob)
{
    const int idx = blockIdx.x * 256 + threadIdx.x;   // 768*768
    const int k = idx / 768, n = idx % 768;
    const int i = k >> 5, kl = k & 31;
    const int quad = kl >> 3, j = kl & 7;
    const int nsg = n >> 4, lane15 = n & 15;
    const int lane = quad * 16 + lane15;
    blob[((size_t)(i * 48 + nsg) * 64 + lane) * 8 + j] = (_Float16)W[idx];
}

// ---------- MFMA GEMM: C[M,N] = A[M,K] @ Bblob (+bias) (+elu+1) ----------
// 32 rows x 64 cols per block, 4 waves (16-col slice each); A f32 double-buffered LDS,
// f16 exact-split 2-MFMA; B frags direct from L2-resident blob.
template<int ACT, int BIAS>
__global__ __launch_bounds__(256, 3) void gemm_mfma(
    const float* __restrict__ A, const _Float16* __restrict__ Bblob,
    const float* __restrict__ bias, float* __restrict__ Cmat,
    int M, int N, int K)
{
    __shared__ float As[2][32][68];
    const int tid = threadIdx.x;
    const int wave = tid >> 6, lane = tid & 63;
    const int lane15 = lane & 15, quad = lane >> 4;
    const int m0 = blockIdx.y * 32;
    const int nsgBase = blockIdx.x * 4 + wave;   // this wave's 16-col group
    const int nchunks = K >> 6;

    const half8* __restrict__ Bc = (const half8*)Bblob;

    // stage chunk 0
    #pragma unroll
    for (int u = 0; u < 2; ++u) {
        int c = tid + u * 256;
        int row = c >> 4, col = (c & 15) * 4;
        *(float4*)&As[0][row][col] = *(const float4*)&A[(size_t)(m0 + row) * K + col];
    }
    __syncthreads();

    f32x4 acc[2];
    acc[0] = (f32x4){0.f, 0.f, 0.f, 0.f};
    acc[1] = (f32x4){0.f, 0.f, 0.f, 0.f};

    for (int ch = 0; ch < nchunks; ++ch) {
        const int buf = ch & 1;
        float4 pre[2];
        if (ch + 1 < nchunks) {
            #pragma unroll
            for (int u = 0; u < 2; ++u) {
                int c = tid + u * 256;
                int row = c >> 4, col = (c & 15) * 4;
                pre[u] = *(const float4*)&A[(size_t)(m0 + row) * K + (ch + 1) * 64 + col];
            }
        }
        #pragma unroll
        for (int kt = 0; kt < 2; ++kt) {
            half8 bb = Bc[(size_t)((ch * 2 + kt) * 48 + nsgBase) * 64 + lane];
            #pragma unroll
            for (int ms = 0; ms < 2; ++ms) {
                float f[8];
                *(float4*)&f[0] = *(const float4*)&As[buf][ms * 16 + lane15][kt * 32 + quad * 8];
                *(float4*)&f[4] = *(const float4*)&As[buf][ms * 16 + lane15][kt * 32 + quad * 8 + 4];
                half8 ah, al;
                split8_f16(f, ah, al);
                acc[ms] = __builtin_amdgcn_mfma_f32_16x16x32_f16(ah, bb, acc[ms], 0, 0, 0);
                acc[ms] = __builtin_amdgcn_mfma_f32_16x16x32_f16(al, bb, acc[ms], 0, 0, 0);
            }
        }
        if (ch + 1 < nchunks) {
            #pragma unroll
            for (int u = 0; u < 2; ++u) {
                int c = tid + u * 256;
                int row = c >> 4, col = (c & 15) * 4;
                *(float4*)&As[1 - buf][row][col] = pre[u];
            }
        }
        __syncthreads();
    }

    // epilogue: C/D layout col=lane15, row=quad*4+r
    const int coln = blockIdx.x * 64 + wave * 16 + lane15;
    #pragma unroll
    for (int ms = 0; ms < 2; ++ms)
        #pragma unroll
        for (int r = 0; r < 4; ++r) {
            int row = m0 + ms * 16 + quad * 4 + r;
            float v = acc[ms][r];
            if (BIAS) v += bias[coln];
            if (ACT) v = elu1(v);
            Cmat[(size_t)row * N + coln] = v;
        }
}

// ---------- prep: W -> f16 fragment-major blob (map kernel, 4096x128) ----------
__global__ __launch_bounds__(256) void prep_w(
    const float* __restrict__ Wks, const float* __restrict__ Wvs,
    _Float16* __restrict__ Wblob)
{
    const int idx = blockIdx.x * 256 + threadIdx.x;   // 4096*128
    const int kk = idx >> 7, n = idx & 127;
    float f = (n < 64) ? Wks[(size_t)kk * 64 + n] : Wvs[(size_t)kk * 64 + (n - 64)];
    const int i = kk >> 6, kl = kk & 63;
    const int ks = kl >> 5, quad = (kl >> 3) & 3, j = kl & 7;
    const int nsg = n >> 4, lane15 = n & 15;
    const int lane = quad * 16 + lane15;
    const size_t off = ((size_t)(((i * 2 + ks) * 8 + nsg)) * 64 + lane) * 8 + j;
    Wblob[off] = (_Float16)f;   // RNE
}

// ---------- MFMA mapped features, f16 exact-split, direct-global B ----------
__global__ __launch_bounds__(256, 3) void map_f16(
    const float* __restrict__ kbuf, const float* __restrict__ vbuf,
    const _Float16* __restrict__ Wblob,
    float* __restrict__ kkv, float* __restrict__ vvv)
{
    __shared__ float kS[32][68];

    const int tid = threadIdx.x;
    const int p0 = blockIdx.x * 32;
    const int wave = tid >> 6, lane = tid & 63;
    const int lane15 = lane & 15, quad = lane >> 4;

    #pragma unroll
    for (int u = 0; u < 2; ++u) {
        int c = tid + u * 256;
        int row = c >> 4, col = (c & 15) * 4;
        *(float4*)&kS[row][col] = *(const float4*)&kbuf[(size_t)(p0 + row) * 64 + col];
    }

    float vr[2][2][8];
    #pragma unroll
    for (int ms = 0; ms < 2; ++ms) {
        const size_t pbase = (size_t)(p0 + ms * 16 + lane15) * 64;
        #pragma unroll
        for (int ks = 0; ks < 2; ++ks) {
            *(float4*)&vr[ms][ks][0] = *(const float4*)&vbuf[pbase + ks * 32 + quad * 8];
            *(float4*)&vr[ms][ks][4] = *(const float4*)&vbuf[pbase + ks * 32 + quad * 8 + 4];
        }
    }

    __syncthreads();

    const half8* __restrict__ Wc = (const half8*)Wblob;

    f32x4 acc[2][2];
    #pragma unroll
    for (int ms = 0; ms < 2; ++ms)
        #pragma unroll
        for (int ns = 0; ns < 2; ++ns)
            acc[ms][ns] = (f32x4){0.f, 0.f, 0.f, 0.f};

    half8 bA[4], bB[4];
    float kA[2], kB[2];

    auto loadB = [&](half8* b, int i) {
        #pragma unroll
        for (int ks = 0; ks < 2; ++ks)
            #pragma unroll
            for (int nsl = 0; nsl < 2; ++nsl)
                b[ks * 2 + nsl] = Wc[(size_t)((i * 2 + ks) * 8 + wave * 2 + nsl) * 64 + lane];
    };
    auto loadK = [&](float* kf, int i) {
        kf[0] = kS[lane15][i];
        kf[1] = kS[16 + lane15][i];
    };
    auto compute = [&](const half8* b, const float* kf) {
        #pragma unroll
        for (int ks = 0; ks < 2; ++ks) {
            half8 ah[2], al[2];
            #pragma unroll
            for (int ms = 0; ms < 2; ++ms) {
                union { fp16x2 h2[4]; half8 h8; } uh, ul;
                #pragma unroll
                for (int jp = 0; jp < 4; ++jp) {
                    float pa = kf[ms] * vr[ms][ks][2 * jp];
                    float pb = kf[ms] * vr[ms][ks][2 * jp + 1];
                    fp16x2 hh = __builtin_amdgcn_cvt_pkrtz(pa, pb);
                    uh.h2[jp] = hh;
                    ul.h2[jp] = __builtin_amdgcn_cvt_pkrtz(pa - (float)hh[0], pb - (float)hh[1]);
                }
                ah[ms] = uh.h8; al[ms] = ul.h8;
            }
            #pragma unroll
            for (int nsl = 0; nsl < 2; ++nsl) {
                half8 bb = b[ks * 2 + nsl];
                #pragma unroll
                for (int ms = 0; ms < 2; ++ms) {
                    acc[ms][nsl] = __builtin_amdgcn_mfma_f32_16x16x32_f16(ah[ms], bb, acc[ms][nsl], 0, 0, 0);
                    acc[ms][nsl] = __builtin_amdgcn_mfma_f32_16x16x32_f16(al[ms], bb, acc[ms][nsl], 0, 0, 0);
                }
            }
        }
    };

    loadB(bA, 0); loadK(kA, 0);
    for (int i = 0; i < 64; i += 2) {
        loadB(bB, i + 1); loadK(kB, i + 1);
        compute(bA, kA);
        if (i + 2 < 64) { loadB(bA, i + 2); loadK(kA, i + 2); }
        compute(bB, kB);
    }

    float* dst = (wave >= 2) ? vvv : kkv;
    const int nbase = (wave & 1) * 32;
    #pragma unroll
    for (int ms = 0; ms < 2; ++ms) {
        #pragma unroll
        for (int nsl = 0; nsl < 2; ++nsl) {
            #pragma unroll
            for (int r = 0; r < 4; ++r) {
                int p = p0 + ms * 16 + quad * 4 + r;
                int col = nbase + nsl * 16 + lane15;
                dst[(size_t)p * 64 + col] = acc[ms][nsl][r];
            }
        }
    }
}

// ---------- tail features ----------
__global__ __launch_bounds__(256) void tail_kernel(
    const float* __restrict__ kkv, const float* __restrict__ vvv,
    const float* __restrict__ bks, const float* __restrict__ bvs,
    float* __restrict__ Kt, float* __restrict__ Vt)
{
    const int idx = blockIdx.x * 256 + threadIdx.x;
    const int t = idx / CDIM;
    const int r = idx % CDIM;
    const int d = r & 63;
    const int t0 = t & ~3;
    float ak = bks[d], av = bvs[d];
    for (int tt = t0; tt <= t; ++tt) {
        ak += kkv[(size_t)tt * CDIM + r];
        av += vvv[(size_t)tt * CDIM + r];
    }
    Kt[idx] = ak;
    Vt[idx] = av;
}

// ---------- set features, hierarchical ----------
__global__ __launch_bounds__(256) void set_lower(
    const float* __restrict__ kkv, const float* __restrict__ vvv,
    const float* __restrict__ bks, const float* __restrict__ bvs,
    float* __restrict__ Kset, float* __restrict__ Vset,
    float* __restrict__ scrK, float* __restrict__ scrV)
{
    __shared__ float curK[63][64];
    __shared__ float curV[63][64];
    const int tid = threadIdx.x;
    const int col = tid & 63, grp = tid >> 6;
    const int h = blockIdx.x % NHEAD;
    const int c = blockIdx.x / NHEAD;
    const int t0 = c * 128;
    const float bk = bks[col], bv = bvs[col];

    for (int j = grp; j < 32; j += 4) {
        const float* pk = kkv + (size_t)(t0 + j * 4) * CDIM + h * 64 + col;
        const float* pv = vvv + (size_t)(t0 + j * 4) * CDIM + h * 64 + col;
        float sk = pk[0] + pk[CDIM] + pk[2 * CDIM] + pk[3 * CDIM];
        float sv = pv[0] + pv[CDIM] + pv[2 * CDIM] + pv[3 * CDIM];
        curK[j][col] = sk; curV[j][col] = sv;
        size_t o = ((size_t)(c * 32 + j) * NHEAD + h) * 64 + col;
        Kset[o] = sk + bk; Vset[o] = sv + bv;
    }
    __syncthreads();

    const int LBASE[6] = {0, 32, 48, 56, 60, 62};
    const int GBASE[6] = {0, 512, 768, 896, 960, 992};
    #pragma unroll
    for (int li = 1; li < 6; ++li) {
        const int ns = 32 >> li;
        for (int j = grp; j < ns; j += 4) {
            float sk = curK[LBASE[li - 1] + 2 * j][col] + curK[LBASE[li - 1] + 2 * j + 1][col];
            float sv = curV[LBASE[li - 1] + 2 * j][col] + curV[LBASE[li - 1] + 2 * j + 1][col];
            curK[LBASE[li] + j][col] = sk; curV[LBASE[li] + j][col] = sv;
            size_t o = ((size_t)(GBASE[li] + c * ns + j) * NHEAD + h) * 64 + col;
            Kset[o] = sk + bk; Vset[o] = sv + bv;
        }
        __syncthreads();
    }

    if (grp == 0) {
        scrK[((size_t)h * 16 + c) * 64 + col] = curK[62][col];
        scrV[((size_t)h * 16 + c) * 64 + col] = curV[62][col];
    }
}

__global__ __launch_bounds__(256) void set_upper(
    const float* __restrict__ scrK, const float* __restrict__ scrV,
    const float* __restrict__ bks, const float* __restrict__ bvs,
    float* __restrict__ Kset, float* __restrict__ Vset)
{
    __shared__ float cK[15][64], cV[15][64];
    const int h = blockIdx.x;
    const int tid = threadIdx.x, col = tid & 63, grp = tid >> 6;
    const float bk = bks[col], bv = bvs[col];

    for (int j = grp; j < 8; j += 4) {
        float sk = scrK[((size_t)h * 16 + 2 * j) * 64 + col] + scrK[((size_t)h * 16 + 2 * j + 1) * 64 + col];
        float sv = scrV[((size_t)h * 16 + 2 * j) * 64 + col] + scrV[((size_t)h * 16 + 2 * j + 1) * 64 + col];
        cK[j][col] = sk; cV[j][col] = sv;
        size_t o = ((size_t)(1008 + j) * NHEAD + h) * 64 + col;
        Kset[o] = sk + bk; Vset[o] = sv + bv;
    }
    __syncthreads();
    const int LB[4] = {0, 8, 12, 14};
    const int GB[4] = {1008, 1016, 1020, 1022};
    #pragma unroll
    for (int li = 1; li < 4; ++li) {
        const int ns = 8 >> li;
        for (int j = grp; j < ns; j += 4) {
            float sk = cK[LB[li - 1] + 2 * j][col] + cK[LB[li - 1] + 2 * j + 1][col];
            float sv = cV[LB[li - 1] + 2 * j][col] + cV[LB[li - 1] + 2 * j + 1][col];
            cK[LB[li] + j][col] = sk; cV[LB[li] + j][col] = sv;
            size_t o = ((size_t)(GB[li] + j) * NHEAD + h) * 64 + col;
            Kset[o] = sk + bk; Vset[o] = sv + bv;
        }
        __syncthreads();
    }
}

// ---------- MFMA flash attention: 32 queries/block, QK split-bf16 3-MFMA, PV bf16 ----------
__global__ __launch_bounds__(256, 3) void attn_mfma(
    const float* __restrict__ qbuf, const float* __restrict__ Kset,
    const float* __restrict__ Vset, const float* __restrict__ Ktail,
    const float* __restrict__ Vtail, float* __restrict__ attout)
{
    __shared__ float vS[64][66];
    __shared__ float sS[32][68];
    __shared__ float mrow[32], lrow[32], arow[32];
    __shared__ float red[32][8];
    __shared__ int   sid[64], send[64];

    const int tid = threadIdx.x;
    const int b   = 63 - (blockIdx.x / NHEAD);   // heavy blocks dispatched first
    const int h   = blockIdx.x % NHEAD;
    const int T0  = b * 32;
    const int wave = tid >> 6, lane = tid & 63;
    const int lane15 = lane & 15, quad = lane >> 4;

    const int Tend = T0 + 32;
    const int LOFF[10] = {0, 512, 768, 896, 960, 992, 1008, 1016, 1020, 1022};
    int pfx[10], Vtot = 0;
    #pragma unroll
    for (int li = 0; li < 10; ++li) { pfx[li] = Vtot; Vtot += Tend >> (li + 2); }

    short8 Qhi[2][2], Qlo[2][2];
    #pragma unroll
    for (int ms = 0; ms < 2; ++ms)
        #pragma unroll
        for (int kt = 0; kt < 2; ++kt) {
            const float* qp = qbuf + ((size_t)(T0 + ms * 16 + lane15) * NHEAD + h) * 64 + kt * 32 + quad * 8;
            float f[8];
            *(float4*)&f[0] = *(const float4*)qp;
            *(float4*)&f[4] = *(const float4*)(qp + 4);
            split8_bf16(f, Qhi[ms][kt], Qlo[ms][kt]);
        }

    if (tid < 32) { mrow[tid] = -1e30f; lrow[tid] = 0.f; }

    f32x4 oacc[2];
    oacc[0] = (f32x4){0.f, 0.f, 0.f, 0.f};
    oacc[1] = (f32x4){0.f, 0.f, 0.f, 0.f};

    const int ntiles = (Vtot + 63) >> 6;
    const int row = tid >> 3, part = tid & 7;

    for (int tile = 0; tile < ntiles; ++tile) {
        __syncthreads();

        if (tid < 64) {
            int j = tile * 64 + tid;
            int s_ = 0, e_ = 0x7fffffff;
            if (j < Vtot) {
                int li = 0;
                #pragma unroll
                for (int u = 1; u < 10; ++u) if (j >= pfx[u]) li = u;
                int idx = j - pfx[li];
                s_ = LOFF[li] + idx;
                e_ = (idx + 1) << (li + 2);
            }
            sid[tid] = s_; send[tid] = e_;
        }
        __syncthreads();

        #pragma unroll
        for (int i = 0; i < 4; ++i) {
            int s  = (tid >> 4) + 16 * i;
            int d4 = tid & 15;
            *(float4*)&vS[s][d4 * 4] =
                *(const float4*)&Vset[((size_t)sid[s] * NHEAD + h) * 64 + d4 * 4];
        }

        short8 Khi[2], Klo[2];
        {
            const int sK = sid[wave * 16 + lane15];
            const float* kp = Kset + ((size_t)sK * NHEAD + h) * 64 + quad * 8;
            #pragma unroll
            for (int kt = 0; kt < 2; ++kt) {
                float f[8];
                *(float4*)&f[0] = *(const float4*)(kp + kt * 32);
                *(float4*)&f[4] = *(const float4*)(kp + kt * 32 + 4);
                split8_bf16(f, Khi[kt], Klo[kt]);
            }
        }

        f32x4 lacc[2];
        lacc[0] = (f32x4){0.f, 0.f, 0.f, 0.f};
        lacc[1] = (f32x4){0.f, 0.f, 0.f, 0.f};
        #pragma unroll
        for (int kt = 0; kt < 2; ++kt)
            #pragma unroll
            for (int ms = 0; ms < 2; ++ms) {
                lacc[ms] = __builtin_amdgcn_mfma_f32_16x16x32_bf16(Qhi[ms][kt], Khi[kt], lacc[ms], 0, 0, 0);
                lacc[ms] = __builtin_amdgcn_mfma_f32_16x16x32_bf16(Qlo[ms][kt], Khi[kt], lacc[ms], 0, 0, 0);
                lacc[ms] = __builtin_amdgcn_mfma_f32_16x16x32_bf16(Qhi[ms][kt], Klo[kt], lacc[ms], 0, 0, 0);
            }

        {
            const int sendv = send[wave * 16 + lane15];
            #pragma unroll
            for (int ms = 0; ms < 2; ++ms)
                #pragma unroll
                for (int r = 0; r < 4; ++r) {
                    int qrow = ms * 16 + quad * 4 + r;
                    bool ok = (T0 + qrow + 1) >= sendv;
                    sS[qrow][wave * 16 + lane15] = ok ? lacc[ms][r] * 0.125f : -1e30f;
                }
        }
        __syncthreads();

        float mx = -3e38f;
        for (int s = part; s < 64; s += 8) mx = fmaxf(mx, sS[row][s]);
        red[row][part] = mx;
        __syncthreads();
        if (tid < 32) {
            float rmax = red[tid][0];
            #pragma unroll
            for (int u = 1; u < 8; ++u) rmax = fmaxf(rmax, red[tid][u]);
            float mold = mrow[tid];
            float mnew = fmaxf(mold, rmax);
            arow[tid] = __expf(mold - mnew);
            mrow[tid] = mnew;
        }
        __syncthreads();

        float sum = 0.f;
        const float mn = mrow[row];
        for (int s = part; s < 64; s += 8) {
            float v0 = sS[row][s];
            float p = v0 > -1e29f ? __expf(v0 - mn) : 0.f;
            sS[row][s] = p;
            sum += p;
        }
        red[row][part] = sum;
        __syncthreads();
        if (tid < 32) {
            float t = 0.f;
            #pragma unroll
            for (int u = 0; u < 8; ++u) t += red[tid][u];
            lrow[tid] = arow[tid] * lrow[tid] + t;
        }

        #pragma unroll
        for (int ms = 0; ms < 2; ++ms)
            #pragma unroll
            for (int r = 0; r < 4; ++r)
                oacc[ms][r] *= arow[ms * 16 + quad * 4 + r];
        __syncthreads();

        #pragma unroll
        for (int kt = 0; kt < 2; ++kt) {
            short8 Pf[2];
            #pragma unroll
            for (int ms = 0; ms < 2; ++ms) {
                const float* pp = &sS[ms * 16 + lane15][kt * 32 + quad * 8];
                float f[8];
                *(float4*)&f[0] = *(const float4*)pp;
                *(float4*)&f[4] = *(const float4*)(pp + 4);
                unsigned w[4];
                #pragma unroll
                for (int p = 0; p < 4; ++p) w[p] = pack2_bf16_rne(f[2 * p], f[2 * p + 1]);
                Pf[ms] = mk_short8(w);
            }
            unsigned vw[4];
            #pragma unroll
            for (int jp = 0; jp < 4; ++jp) {
                float a = vS[kt * 32 + quad * 8 + 2 * jp][wave * 16 + lane15];
                float bb = vS[kt * 32 + quad * 8 + 2 * jp + 1][wave * 16 + lane15];
                vw[jp] = pack2_bf16_rne(a, bb);
            }
            short8 Vf = mk_short8(vw);
            #pragma unroll
            for (int ms = 0; ms < 2; ++ms)
                oacc[ms] = __builtin_amdgcn_mfma_f32_16x16x32_bf16(Pf[ms], Vf, oacc[ms], 0, 0, 0);
        }
    }

    __syncthreads();

    {
        const float* qr = qbuf  + ((size_t)(T0 + row) * NHEAD + h) * 64;
        const float* kr = Ktail + ((size_t)(T0 + row) * NHEAD + h) * 64;
        float dp = 0.f;
        for (int d = part; d < 64; d += 8) dp += qr[d] * kr[d];
        red[row][part] = dp;
    }
    __syncthreads();
    if (tid < 32) {
        float tl = 0.f;
        #pragma unroll
        for (int u = 0; u < 8; ++u) tl += red[tid][u];
        tl *= 0.125f;
        float mold = mrow[tid];
        float mf = fmaxf(mold, tl);
        float al = __expf(mold - mf);
        float pt = __expf(tl - mf);
        float lf = al * lrow[tid] + pt;
        arow[tid] = al;
        lrow[tid] = pt / lf;
        mrow[tid] = 1.f / lf;
    }
    __syncthreads();

    #pragma unroll
    for (int ms = 0; ms < 2; ++ms)
        #pragma unroll
        for (int r = 0; r < 4; ++r) {
            int qrow = ms * 16 + quad * 4 + r;
            int col = wave * 16 + lane15;
            float al_inv = arow[qrow] * mrow[qrow];
            float ptinv = lrow[qrow];
            size_t base = ((size_t)(T0 + qrow) * NHEAD + h) * 64 + col;
            attout[base] = oacc[ms][r] * al_inv + ptinv * Vtail[base];
        }
}

extern "C" void kernel_launch(void* const* d_in, const int* in_sizes, int n_in,
                              void* d_out, int out_size, void* d_ws, size_t ws_size,
                              hipStream_t stream)
{
    const float* x   = (const float*)d_in[0];
    const float* Wq  = (const float*)d_in[1];
    const float* Wk  = (const float*)d_in[2];
    const float* Wv  = (const float*)d_in[3];
    const float* Wks = (const float*)d_in[4];
    const float* bks = (const float*)d_in[5];
    const float* Wvs = (const float*)d_in[6];
    const float* bvs = (const float*)d_in[7];
    const float* Wc  = (const float*)d_in[8];
    const float* bc  = (const float*)d_in[9];
    float* out = (float*)d_out;

    float* ws = (float*)d_ws;
    const size_t TC = (size_t)TLEN * CDIM;
    float* q      = ws;
    float* k      = q + TC;
    float* v      = k + TC;
    float* kkv    = v + TC;
    float* vvv    = kkv + TC;
    float* Kt     = vvv + TC;
    float* Vt     = Kt + TC;
    float* Kset   = Vt + TC;
    float* Vset   = Kset + (size_t)NSETS * CDIM;
    float* attout = Vset + (size_t)NSETS * CDIM;
    // Aliases into attout (1.57M floats; attout written only at attn_mfma, after all alias readers):
    //   [0, 262144)           map Wblob (halfs: 524288)
    //   [262144, 1146880)     Wq/Wk/Wv f16 blobs (294912 floats each)
    //   [1146880, 1171456)    scrK/scrV
    _Float16* WblobMap = (_Float16*)attout;
    _Float16* blobQ = (_Float16*)(attout + 262144);
    _Float16* blobK = (_Float16*)(attout + 262144 + 294912);
    _Float16* blobV = (_Float16*)(attout + 262144 + 2 * 294912);
    float* scrK = attout + 1146880;
    float* scrV = scrK + 12 * 16 * 64;
    // Wc blob lives in the k buffer (dead after map_f16); prep'd after map_f16.
    _Float16* blobC = (_Float16*)k;

    const int WB = (768 * 768) / 256;   // 2304 blocks
    prep_w768<<<WB, 256, 0, stream>>>(Wq, blobQ);
    prep_w768<<<WB, 256, 0, stream>>>(Wk, blobK);
    prep_w768<<<WB, 256, 0, stream>>>(Wv, blobV);
    prep_w<<<(4096 * 128) / 256, 256, 0, stream>>>(Wks, Wvs, WblobMap);

    dim3 gg(CDIM / 64, TLEN / 32);   // (12, 64) = 768 blocks
    gemm_mfma<1, 0><<<gg, 256, 0, stream>>>(x, blobQ, nullptr, q, TLEN, CDIM, CDIM);
    gemm_mfma<1, 0><<<gg, 256, 0, stream>>>(x, blobK, nullptr, k, TLEN, CDIM, CDIM);
    gemm_mfma<0, 0><<<gg, 256, 0, stream>>>(x, blobV, nullptr, v, TLEN, CDIM, CDIM);

    map_f16<<<(TLEN * NHEAD) / 32, 256, 0, stream>>>(k, v, WblobMap, kkv, vvv);

    prep_w768<<<WB, 256, 0, stream>>>(Wc, blobC);

    tail_kernel<<<(TLEN * CDIM) / 256, 256, 0, stream>>>(kkv, vvv, bks, bvs, Kt, Vt);

    set_lower<<<16 * NHEAD, 256, 0, stream>>>(kkv, vvv, bks, bvs, Kset, Vset, scrK, scrV);
    set_upper<<<NHEAD, 256, 0, stream>>>(scrK, scrV, bks, bvs, Kset, Vset);

    attn_mfma<<<(TLEN / 32) * NHEAD, 256, 0, stream>>>(q, Kset, Vset, Kt, Vt, attout);

    gemm_mfma<0, 1><<<gg, 256, 0, stream>>>(attout, blobC, bc, out, TLEN, CDIM, CDIM);
}

// Round 9
// 282.892 us; speedup vs baseline: 5.9404x; 1.2008x over previous
//
#include <hip/hip_runtime.h>
#include <cstdint>

#define NHEAD 12
#define TLEN 2048
#define CDIM 768
#define NSETS 1023   // 512+256+128+64+32+16+8+4+2+1

typedef __attribute__((ext_vector_type(8))) _Float16 half8;
typedef __attribute__((ext_vector_type(2))) __fp16 fp16x2;
typedef __attribute__((ext_vector_type(8))) short short8;   // 8 bf16
typedef __attribute__((ext_vector_type(4))) float f32x4;

__device__ __forceinline__ float elu1(float x) { return x > 0.f ? x + 1.f : __expf(x); }

__device__ __forceinline__ unsigned pack2_bf16_trunc(float a, float b) {
    unsigned ua = __float_as_uint(a), ub = __float_as_uint(b);
    return __builtin_amdgcn_perm(ub, ua, 0x07060302);
}
__device__ __forceinline__ unsigned pack2_bf16_rne(float a, float b) {
    unsigned ua = __float_as_uint(a), ub = __float_as_uint(b);
    ua = ua + 0x7fff + ((ua >> 16) & 1);
    ub = ub + 0x7fff + ((ub >> 16) & 1);
    return (ub & 0xffff0000u) | (ua >> 16);
}
__device__ __forceinline__ short8 mk_short8(const unsigned* u) {
    union { unsigned w[4]; short8 s; } x;
    x.w[0] = u[0]; x.w[1] = u[1]; x.w[2] = u[2]; x.w[3] = u[3];
    return x.s;
}
__device__ __forceinline__ void split8_bf16(const float* f, short8& hi, short8& lo) {
    unsigned hp[4], lp[4];
    #pragma unroll
    for (int p = 0; p < 4; ++p) {
        float a = f[2 * p], b = f[2 * p + 1];
        unsigned ua = __float_as_uint(a), ub = __float_as_uint(b);
        hp[p] = __builtin_amdgcn_perm(ub, ua, 0x07060302);
        float ra = a - __uint_as_float(ua & 0xffff0000u);
        float rb = b - __uint_as_float(ub & 0xffff0000u);
        lp[p] = pack2_bf16_trunc(ra, rb);
    }
    hi = mk_short8(hp); lo = mk_short8(lp);
}
__device__ __forceinline__ void split8_f16(const float* f, half8& hi, half8& lo) {
    union { fp16x2 h2[4]; half8 h8; } uh, ul;
    #pragma unroll
    for (int jp = 0; jp < 4; ++jp) {
        float a = f[2 * jp], b = f[2 * jp + 1];
        fp16x2 hh = __builtin_amdgcn_cvt_pkrtz(a, b);
        uh.h2[jp] = hh;
        ul.h2[jp] = __builtin_amdgcn_cvt_pkrtz(a - (float)hh[0], b - (float)hh[1]);
    }
    hi = uh.h8; lo = ul.h8;
}

// ---------- prep: 768x768 W -> f16 fragment-major blob ----------
__global__ __launch_bounds__(256) void prep_w768(
    const float* __restrict__ W, _Float16* __restrict__ blob)
{
    const int idx = blockIdx.x * 256 + threadIdx.x;
    const int k = idx / 768, n = idx % 768;
    const int i = k >> 5, kl = k & 31;
    const int quad = kl >> 3, j = kl & 7;
    const int nsg = n >> 4, lane15 = n & 15;
    const int lane = quad * 16 + lane15;
    blob[((size_t)(i * 48 + nsg) * 64 + lane) * 8 + j] = (_Float16)W[idx];
}

// fused Q/K/V prep
__global__ __launch_bounds__(256) void prep_w768x3(
    const float* __restrict__ Wq, const float* __restrict__ Wk,
    const float* __restrict__ Wv, _Float16* __restrict__ blobs)
{
    const int g = blockIdx.x;          // 3*2304
    const int sel = g / 2304;
    const float* W = sel == 0 ? Wq : (sel == 1 ? Wk : Wv);
    _Float16* blob = blobs + (size_t)sel * 589824;
    const int idx = (g % 2304) * 256 + threadIdx.x;
    const int k = idx / 768, n = idx % 768;
    const int i = k >> 5, kl = k & 31;
    const int quad = kl >> 3, j = kl & 7;
    const int nsg = n >> 4, lane15 = n & 15;
    const int lane = quad * 16 + lane15;
    blob[((size_t)(i * 48 + nsg) * 64 + lane) * 8 + j] = (_Float16)W[idx];
}

// ---------- MFMA GEMM core (used for final projection) ----------
template<int ACT, int BIAS>
__global__ __launch_bounds__(256, 3) void gemm_mfma(
    const float* __restrict__ A, const _Float16* __restrict__ Bblob,
    const float* __restrict__ bias, float* __restrict__ Cmat,
    int M, int N, int K)
{
    __shared__ float As[2][32][68];
    const int tid = threadIdx.x;
    const int wave = tid >> 6, lane = tid & 63;
    const int lane15 = lane & 15, quad = lane >> 4;
    const int m0 = blockIdx.y * 32;
    const int nsgBase = blockIdx.x * 4 + wave;
    const int nchunks = K >> 6;

    const half8* __restrict__ Bc = (const half8*)Bblob;

    #pragma unroll
    for (int u = 0; u < 2; ++u) {
        int c = tid + u * 256;
        int row = c >> 4, col = (c & 15) * 4;
        *(float4*)&As[0][row][col] = *(const float4*)&A[(size_t)(m0 + row) * K + col];
    }
    __syncthreads();

    f32x4 acc[2];
    acc[0] = (f32x4){0.f, 0.f, 0.f, 0.f};
    acc[1] = (f32x4){0.f, 0.f, 0.f, 0.f};

    for (int ch = 0; ch < nchunks; ++ch) {
        const int buf = ch & 1;
        float4 pre[2];
        if (ch + 1 < nchunks) {
            #pragma unroll
            for (int u = 0; u < 2; ++u) {
                int c = tid + u * 256;
                int row = c >> 4, col = (c & 15) * 4;
                pre[u] = *(const float4*)&A[(size_t)(m0 + row) * K + (ch + 1) * 64 + col];
            }
        }
        #pragma unroll
        for (int kt = 0; kt < 2; ++kt) {
            half8 bb = Bc[(size_t)((ch * 2 + kt) * 48 + nsgBase) * 64 + lane];
            #pragma unroll
            for (int ms = 0; ms < 2; ++ms) {
                float f[8];
                *(float4*)&f[0] = *(const float4*)&As[buf][ms * 16 + lane15][kt * 32 + quad * 8];
                *(float4*)&f[4] = *(const float4*)&As[buf][ms * 16 + lane15][kt * 32 + quad * 8 + 4];
                half8 ah, al;
                split8_f16(f, ah, al);
                acc[ms] = __builtin_amdgcn_mfma_f32_16x16x32_f16(ah, bb, acc[ms], 0, 0, 0);
                acc[ms] = __builtin_amdgcn_mfma_f32_16x16x32_f16(al, bb, acc[ms], 0, 0, 0);
            }
        }
        if (ch + 1 < nchunks) {
            #pragma unroll
            for (int u = 0; u < 2; ++u) {
                int c = tid + u * 256;
                int row = c >> 4, col = (c & 15) * 4;
                *(float4*)&As[1 - buf][row][col] = pre[u];
            }
        }
        __syncthreads();
    }

    const int coln = blockIdx.x * 64 + wave * 16 + lane15;
    #pragma unroll
    for (int ms = 0; ms < 2; ++ms)
        #pragma unroll
        for (int r = 0; r < 4; ++r) {
            int row = m0 + ms * 16 + quad * 4 + r;
            float v = acc[ms][r];
            if (BIAS) v += bias[coln];
            if (ACT) v = elu1(v);
            Cmat[(size_t)row * N + coln] = v;
        }
}

// ---------- fused QKV projection: 3 GEMMs in one launch ----------
__global__ __launch_bounds__(256, 3) void gemm_qkv(
    const float* __restrict__ A, const _Float16* __restrict__ blobs,
    float* __restrict__ outbase)
{
    __shared__ float As[2][32][68];
    const int which = blockIdx.x / 12;
    const int bx = blockIdx.x % 12;
    const _Float16* Bblob = blobs + (size_t)which * 589824;
    float* Cmat = outbase + (size_t)which * ((size_t)TLEN * CDIM);
    const bool act = which < 2;

    const int tid = threadIdx.x;
    const int wave = tid >> 6, lane = tid & 63;
    const int lane15 = lane & 15, quad = lane >> 4;
    const int m0 = blockIdx.y * 32;
    const int nsgBase = bx * 4 + wave;
    const int nchunks = CDIM >> 6;   // 12

    const half8* __restrict__ Bc = (const half8*)Bblob;

    #pragma unroll
    for (int u = 0; u < 2; ++u) {
        int c = tid + u * 256;
        int row = c >> 4, col = (c & 15) * 4;
        *(float4*)&As[0][row][col] = *(const float4*)&A[(size_t)(m0 + row) * CDIM + col];
    }
    __syncthreads();

    f32x4 acc[2];
    acc[0] = (f32x4){0.f, 0.f, 0.f, 0.f};
    acc[1] = (f32x4){0.f, 0.f, 0.f, 0.f};

    for (int ch = 0; ch < nchunks; ++ch) {
        const int buf = ch & 1;
        float4 pre[2];
        if (ch + 1 < nchunks) {
            #pragma unroll
            for (int u = 0; u < 2; ++u) {
                int c = tid + u * 256;
                int row = c >> 4, col = (c & 15) * 4;
                pre[u] = *(const float4*)&A[(size_t)(m0 + row) * CDIM + (ch + 1) * 64 + col];
            }
        }
        #pragma unroll
        for (int kt = 0; kt < 2; ++kt) {
            half8 bb = Bc[(size_t)((ch * 2 + kt) * 48 + nsgBase) * 64 + lane];
            #pragma unroll
            for (int ms = 0; ms < 2; ++ms) {
                float f[8];
                *(float4*)&f[0] = *(const float4*)&As[buf][ms * 16 + lane15][kt * 32 + quad * 8];
                *(float4*)&f[4] = *(const float4*)&As[buf][ms * 16 + lane15][kt * 32 + quad * 8 + 4];
                half8 ah, al;
                split8_f16(f, ah, al);
                acc[ms] = __builtin_amdgcn_mfma_f32_16x16x32_f16(ah, bb, acc[ms], 0, 0, 0);
                acc[ms] = __builtin_amdgcn_mfma_f32_16x16x32_f16(al, bb, acc[ms], 0, 0, 0);
            }
        }
        if (ch + 1 < nchunks) {
            #pragma unroll
            for (int u = 0; u < 2; ++u) {
                int c = tid + u * 256;
                int row = c >> 4, col = (c & 15) * 4;
                *(float4*)&As[1 - buf][row][col] = pre[u];
            }
        }
        __syncthreads();
    }

    const int coln = bx * 64 + wave * 16 + lane15;
    #pragma unroll
    for (int ms = 0; ms < 2; ++ms)
        #pragma unroll
        for (int r = 0; r < 4; ++r) {
            int row = m0 + ms * 16 + quad * 4 + r;
            float v = acc[ms][r];
            if (act) v = elu1(v);
            Cmat[(size_t)row * CDIM + coln] = v;
        }
}

// ---------- prep: map W -> f16 fragment-major blob (4096x128) ----------
__global__ __launch_bounds__(256) void prep_w(
    const float* __restrict__ Wks, const float* __restrict__ Wvs,
    _Float16* __restrict__ Wblob)
{
    const int idx = blockIdx.x * 256 + threadIdx.x;
    const int kk = idx >> 7, n = idx & 127;
    float f = (n < 64) ? Wks[(size_t)kk * 64 + n] : Wvs[(size_t)kk * 64 + (n - 64)];
    const int i = kk >> 6, kl = kk & 63;
    const int ks = kl >> 5, quad = (kl >> 3) & 3, j = kl & 7;
    const int nsg = n >> 4, lane15 = n & 15;
    const int lane = quad * 16 + lane15;
    const size_t off = ((size_t)(((i * 2 + ks) * 8 + nsg)) * 64 + lane) * 8 + j;
    Wblob[off] = (_Float16)f;
}

// ---------- MFMA mapped features v2: wave = 16 pos x 64 N (halved split duplication) ----
__global__ __launch_bounds__(256, 3) void map_f16(
    const float* __restrict__ kbuf, const float* __restrict__ vbuf,
    const _Float16* __restrict__ Wblob,
    float* __restrict__ kkv, float* __restrict__ vvv)
{
    __shared__ float kS[32][68];

    const int tid = threadIdx.x;
    const int p0 = blockIdx.x * 32;
    const int wave = tid >> 6, lane = tid & 63;
    const int lane15 = lane & 15, quad = lane >> 4;
    const int mh = wave & 1;    // position half
    const int nh = wave >> 1;   // output half: 0 -> kkv cols, 1 -> vvv cols

    #pragma unroll
    for (int u = 0; u < 2; ++u) {
        int c = tid + u * 256;
        int row = c >> 4, col = (c & 15) * 4;
        *(float4*)&kS[row][col] = *(const float4*)&kbuf[(size_t)(p0 + row) * 64 + col];
    }

    float vr[2][8];
    {
        const size_t pbase = (size_t)(p0 + mh * 16 + lane15) * 64;
        #pragma unroll
        for (int ks = 0; ks < 2; ++ks) {
            *(float4*)&vr[ks][0] = *(const float4*)&vbuf[pbase + ks * 32 + quad * 8];
            *(float4*)&vr[ks][4] = *(const float4*)&vbuf[pbase + ks * 32 + quad * 8 + 4];
        }
    }
    __syncthreads();

    const half8* __restrict__ Wc = (const half8*)Wblob;

    f32x4 acc[4];
    #pragma unroll
    for (int nsl = 0; nsl < 4; ++nsl) acc[nsl] = (f32x4){0.f, 0.f, 0.f, 0.f};

    half8 bA[4], bB[4];
    float kA, kB;

    auto loadB = [&](half8* b, int s) {
        #pragma unroll
        for (int nsl = 0; nsl < 4; ++nsl)
            b[nsl] = Wc[(size_t)(s * 8 + nh * 4 + nsl) * 64 + lane];
    };
    auto loadK = [&](float& kf, int s) { kf = kS[mh * 16 + lane15][s >> 1]; };
    auto compute = [&](const half8* b, float kf, int s) {
        const int ks = s & 1;
        float f[8];
        #pragma unroll
        for (int j = 0; j < 8; ++j) f[j] = kf * vr[ks][j];
        half8 ah, al;
        split8_f16(f, ah, al);
        #pragma unroll
        for (int nsl = 0; nsl < 4; ++nsl)
            acc[nsl] = __builtin_amdgcn_mfma_f32_16x16x32_f16(ah, b[nsl], acc[nsl], 0, 0, 0);
        #pragma unroll
        for (int nsl = 0; nsl < 4; ++nsl)
            acc[nsl] = __builtin_amdgcn_mfma_f32_16x16x32_f16(al, b[nsl], acc[nsl], 0, 0, 0);
    };

    loadB(bA, 0); loadK(kA, 0);
    for (int s = 0; s < 128; s += 2) {
        loadB(bB, s + 1); loadK(kB, s + 1);
        compute(bA, kA, s);
        if (s + 2 < 128) { loadB(bA, s + 2); loadK(kA, s + 2); }
        compute(bB, kB, s + 1);
    }

    // epilogue: C/D layout col=lane15, row=quad*4+r
    float* dst = nh ? vvv : kkv;
    #pragma unroll
    for (int nsl = 0; nsl < 4; ++nsl)
        #pragma unroll
        for (int r = 0; r < 4; ++r) {
            int p = p0 + mh * 16 + quad * 4 + r;
            int col = nsl * 16 + lane15;
            dst[(size_t)p * 64 + col] = acc[nsl][r];
        }
}

// ---------- set features (levels 2..7) + fused tail cumsum ----------
__global__ __launch_bounds__(256) void set_lower(
    const float* __restrict__ kkv, const float* __restrict__ vvv,
    const float* __restrict__ bks, const float* __restrict__ bvs,
    float* __restrict__ Kset, float* __restrict__ Vset,
    float* __restrict__ scrK, float* __restrict__ scrV,
    float* __restrict__ Kt, float* __restrict__ Vt)
{
    __shared__ float curK[63][64];
    __shared__ float curV[63][64];
    const int tid = threadIdx.x;
    const int col = tid & 63, grp = tid >> 6;
    const int h = blockIdx.x % NHEAD;
    const int c = blockIdx.x / NHEAD;
    const int t0 = c * 128;
    const float bk = bks[col], bv = bvs[col];

    for (int j = grp; j < 32; j += 4) {
        const size_t rbase = (size_t)(t0 + j * 4) * CDIM + h * 64 + col;
        const float* pk = kkv + rbase;
        const float* pv = vvv + rbase;
        float* ptK = Kt + rbase;
        float* ptV = Vt + rbase;
        float sk = bk, sv = bv;
        #pragma unroll
        for (int u = 0; u < 4; ++u) {
            sk += pk[(size_t)u * CDIM];
            sv += pv[(size_t)u * CDIM];
            ptK[(size_t)u * CDIM] = sk;   // tail = bias + within-block cumsum
            ptV[(size_t)u * CDIM] = sv;
        }
        curK[j][col] = sk - bk; curV[j][col] = sv - bv;
        size_t o = ((size_t)(c * 32 + j) * NHEAD + h) * 64 + col;
        Kset[o] = sk; Vset[o] = sv;
    }
    __syncthreads();

    const int LBASE[6] = {0, 32, 48, 56, 60, 62};
    const int GBASE[6] = {0, 512, 768, 896, 960, 992};
    #pragma unroll
    for (int li = 1; li < 6; ++li) {
        const int ns = 32 >> li;
        for (int j = grp; j < ns; j += 4) {
            float sk = curK[LBASE[li - 1] + 2 * j][col] + curK[LBASE[li - 1] + 2 * j + 1][col];
            float sv = curV[LBASE[li - 1] + 2 * j][col] + curV[LBASE[li - 1] + 2 * j + 1][col];
            curK[LBASE[li] + j][col] = sk; curV[LBASE[li] + j][col] = sv;
            size_t o = ((size_t)(GBASE[li] + c * ns + j) * NHEAD + h) * 64 + col;
            Kset[o] = sk + bk; Vset[o] = sv + bv;
        }
        __syncthreads();
    }

    if (grp == 0) {
        scrK[((size_t)h * 16 + c) * 64 + col] = curK[62][col];
        scrV[((size_t)h * 16 + c) * 64 + col] = curV[62][col];
    }
}

__global__ __launch_bounds__(256) void set_upper(
    const float* __restrict__ scrK, const float* __restrict__ scrV,
    const float* __restrict__ bks, const float* __restrict__ bvs,
    float* __restrict__ Kset, float* __restrict__ Vset)
{
    __shared__ float cK[15][64], cV[15][64];
    const int h = blockIdx.x;
    const int tid = threadIdx.x, col = tid & 63, grp = tid >> 6;
    const float bk = bks[col], bv = bvs[col];

    for (int j = grp; j < 8; j += 4) {
        float sk = scrK[((size_t)h * 16 + 2 * j) * 64 + col] + scrK[((size_t)h * 16 + 2 * j + 1) * 64 + col];
        float sv = scrV[((size_t)h * 16 + 2 * j) * 64 + col] + scrV[((size_t)h * 16 + 2 * j + 1) * 64 + col];
        cK[j][col] = sk; cV[j][col] = sv;
        size_t o = ((size_t)(1008 + j) * NHEAD + h) * 64 + col;
        Kset[o] = sk + bk; Vset[o] = sv + bv;
    }
    __syncthreads();
    const int LB[4] = {0, 8, 12, 14};
    const int GB[4] = {1008, 1016, 1020, 1022};
    #pragma unroll
    for (int li = 1; li < 4; ++li) {
        const int ns = 8 >> li;
        for (int j = grp; j < ns; j += 4) {
            float sk = cK[LB[li - 1] + 2 * j][col] + cK[LB[li - 1] + 2 * j + 1][col];
            float sv = cV[LB[li - 1] + 2 * j][col] + cV[LB[li - 1] + 2 * j + 1][col];
            cK[LB[li] + j][col] = sk; cV[LB[li] + j][col] = sv;
            size_t o = ((size_t)(GB[li] + j) * NHEAD + h) * 64 + col;
            Kset[o] = sk + bk; Vset[o] = sv + bv;
        }
        __syncthreads();
    }
}

// ---------- MFMA flash attention ----------
__global__ __launch_bounds__(256, 3) void attn_mfma(
    const float* __restrict__ qbuf, const float* __restrict__ Kset,
    const float* __restrict__ Vset, const float* __restrict__ Ktail,
    const float* __restrict__ Vtail, float* __restrict__ attout)
{
    __shared__ float vS[64][66];
    __shared__ float sS[32][68];
    __shared__ float mrow[32], lrow[32], arow[32];
    __shared__ float red[32][8];
    __shared__ int   sid[64], send[64];

    const int tid = threadIdx.x;
    const int b   = 63 - (blockIdx.x / NHEAD);
    const int h   = blockIdx.x % NHEAD;
    const int T0  = b * 32;
    const int wave = tid >> 6, lane = tid & 63;
    const int lane15 = lane & 15, quad = lane >> 4;

    const int Tend = T0 + 32;
    const int LOFF[10] = {0, 512, 768, 896, 960, 992, 1008, 1016, 1020, 1022};
    int pfx[10], Vtot = 0;
    #pragma unroll
    for (int li = 0; li < 10; ++li) { pfx[li] = Vtot; Vtot += Tend >> (li + 2); }

    short8 Qhi[2][2], Qlo[2][2];
    #pragma unroll
    for (int ms = 0; ms < 2; ++ms)
        #pragma unroll
        for (int kt = 0; kt < 2; ++kt) {
            const float* qp = qbuf + ((size_t)(T0 + ms * 16 + lane15) * NHEAD + h) * 64 + kt * 32 + quad * 8;
            float f[8];
            *(float4*)&f[0] = *(const float4*)qp;
            *(float4*)&f[4] = *(const float4*)(qp + 4);
            split8_bf16(f, Qhi[ms][kt], Qlo[ms][kt]);
        }

    if (tid < 32) { mrow[tid] = -1e30f; lrow[tid] = 0.f; }

    f32x4 oacc[2];
    oacc[0] = (f32x4){0.f, 0.f, 0.f, 0.f};
    oacc[1] = (f32x4){0.f, 0.f, 0.f, 0.f};

    const int ntiles = (Vtot + 63) >> 6;
    const int row = tid >> 3, part = tid & 7;

    for (int tile = 0; tile < ntiles; ++tile) {
        __syncthreads();

        if (tid < 64) {
            int j = tile * 64 + tid;
            int s_ = 0, e_ = 0x7fffffff;
            if (j < Vtot) {
                int li = 0;
                #pragma unroll
                for (int u = 1; u < 10; ++u) if (j >= pfx[u]) li = u;
                int idx = j - pfx[li];
                s_ = LOFF[li] + idx;
                e_ = (idx + 1) << (li + 2);
            }
            sid[tid] = s_; send[tid] = e_;
        }
        __syncthreads();

        #pragma unroll
        for (int i = 0; i < 4; ++i) {
            int s  = (tid >> 4) + 16 * i;
            int d4 = tid & 15;
            *(float4*)&vS[s][d4 * 4] =
                *(const float4*)&Vset[((size_t)sid[s] * NHEAD + h) * 64 + d4 * 4];
        }

        short8 Khi[2], Klo[2];
        {
            const int sK = sid[wave * 16 + lane15];
            const float* kp = Kset + ((size_t)sK * NHEAD + h) * 64 + quad * 8;
            #pragma unroll
            for (int kt = 0; kt < 2; ++kt) {
                float f[8];
                *(float4*)&f[0] = *(const float4*)(kp + kt * 32);
                *(float4*)&f[4] = *(const float4*)(kp + kt * 32 + 4);
                split8_bf16(f, Khi[kt], Klo[kt]);
            }
        }

        f32x4 lacc[2];
        lacc[0] = (f32x4){0.f, 0.f, 0.f, 0.f};
        lacc[1] = (f32x4){0.f, 0.f, 0.f, 0.f};
        #pragma unroll
        for (int kt = 0; kt < 2; ++kt)
            #pragma unroll
            for (int ms = 0; ms < 2; ++ms) {
                lacc[ms] = __builtin_amdgcn_mfma_f32_16x16x32_bf16(Qhi[ms][kt], Khi[kt], lacc[ms], 0, 0, 0);
                lacc[ms] = __builtin_amdgcn_mfma_f32_16x16x32_bf16(Qlo[ms][kt], Khi[kt], lacc[ms], 0, 0, 0);
                lacc[ms] = __builtin_amdgcn_mfma_f32_16x16x32_bf16(Qhi[ms][kt], Klo[kt], lacc[ms], 0, 0, 0);
            }

        {
            const int sendv = send[wave * 16 + lane15];
            #pragma unroll
            for (int ms = 0; ms < 2; ++ms)
                #pragma unroll
                for (int r = 0; r < 4; ++r) {
                    int qrow = ms * 16 + quad * 4 + r;
                    bool ok = (T0 + qrow + 1) >= sendv;
                    sS[qrow][wave * 16 + lane15] = ok ? lacc[ms][r] * 0.125f : -1e30f;
                }
        }
        __syncthreads();

        // softmax pass 1: rowmax (contiguous float4x2 per thread)
        float4* sr = (float4*)&sS[row][0];
        {
            float4 a = sr[part * 2], c4 = sr[part * 2 + 1];
            float mx = fmaxf(fmaxf(fmaxf(a.x, a.y), fmaxf(a.z, a.w)),
                             fmaxf(fmaxf(c4.x, c4.y), fmaxf(c4.z, c4.w)));
            red[row][part] = mx;
        }
        __syncthreads();
        if (tid < 32) {
            float rmax = red[tid][0];
            #pragma unroll
            for (int u = 1; u < 8; ++u) rmax = fmaxf(rmax, red[tid][u]);
            float mold = mrow[tid];
            float mnew = fmaxf(mold, rmax);
            arow[tid] = __expf(mold - mnew);
            mrow[tid] = mnew;
        }
        __syncthreads();

        // pass 2: exp + rowsum
        {
            const float mn = mrow[row];
            float4 a = sr[part * 2], c4 = sr[part * 2 + 1];
            a.x = a.x > -1e29f ? __expf(a.x - mn) : 0.f;
            a.y = a.y > -1e29f ? __expf(a.y - mn) : 0.f;
            a.z = a.z > -1e29f ? __expf(a.z - mn) : 0.f;
            a.w = a.w > -1e29f ? __expf(a.w - mn) : 0.f;
            c4.x = c4.x > -1e29f ? __expf(c4.x - mn) : 0.f;
            c4.y = c4.y > -1e29f ? __expf(c4.y - mn) : 0.f;
            c4.z = c4.z > -1e29f ? __expf(c4.z - mn) : 0.f;
            c4.w = c4.w > -1e29f ? __expf(c4.w - mn) : 0.f;
            sr[part * 2] = a; sr[part * 2 + 1] = c4;
            red[row][part] = (a.x + a.y + a.z + a.w) + (c4.x + c4.y + c4.z + c4.w);
        }
        __syncthreads();
        if (tid < 32) {
            float t = 0.f;
            #pragma unroll
            for (int u = 0; u < 8; ++u) t += red[tid][u];
            lrow[tid] = arow[tid] * lrow[tid] + t;
        }

        #pragma unroll
        for (int ms = 0; ms < 2; ++ms)
            #pragma unroll
            for (int r = 0; r < 4; ++r)
                oacc[ms][r] *= arow[ms * 16 + quad * 4 + r];
        __syncthreads();

        #pragma unroll
        for (int kt = 0; kt < 2; ++kt) {
            short8 Pf[2];
            #pragma unroll
            for (int ms = 0; ms < 2; ++ms) {
                const float* pp = &sS[ms * 16 + lane15][kt * 32 + quad * 8];
                float f[8];
                *(float4*)&f[0] = *(const float4*)pp;
                *(float4*)&f[4] = *(const float4*)(pp + 4);
                unsigned w[4];
                #pragma unroll
                for (int p = 0; p < 4; ++p) w[p] = pack2_bf16_rne(f[2 * p], f[2 * p + 1]);
                Pf[ms] = mk_short8(w);
            }
            unsigned vw[4];
            #pragma unroll
            for (int jp = 0; jp < 4; ++jp) {
                float a = vS[kt * 32 + quad * 8 + 2 * jp][wave * 16 + lane15];
                float bb = vS[kt * 32 + quad * 8 + 2 * jp + 1][wave * 16 + lane15];
                vw[jp] = pack2_bf16_rne(a, bb);
            }
            short8 Vf = mk_short8(vw);
            #pragma unroll
            for (int ms = 0; ms < 2; ++ms)
                oacc[ms] = __builtin_amdgcn_mfma_f32_16x16x32_bf16(Pf[ms], Vf, oacc[ms], 0, 0, 0);
        }
    }

    __syncthreads();

    {
        const float* qr = qbuf  + ((size_t)(T0 + row) * NHEAD + h) * 64;
        const float* kr = Ktail + ((size_t)(T0 + row) * NHEAD + h) * 64;
        float dp = 0.f;
        for (int d = part; d < 64; d += 8) dp += qr[d] * kr[d];
        red[row][part] = dp;
    }
    __syncthreads();
    if (tid < 32) {
        float tl = 0.f;
        #pragma unroll
        for (int u = 0; u < 8; ++u) tl += red[tid][u];
        tl *= 0.125f;
        float mold = mrow[tid];
        float mf = fmaxf(mold, tl);
        float al = __expf(mold - mf);
        float pt = __expf(tl - mf);
        float lf = al * lrow[tid] + pt;
        arow[tid] = al;
        lrow[tid] = pt / lf;
        mrow[tid] = 1.f / lf;
    }
    __syncthreads();

    #pragma unroll
    for (int ms = 0; ms < 2; ++ms)
        #pragma unroll
        for (int r = 0; r < 4; ++r) {
            int qrow = ms * 16 + quad * 4 + r;
            int col = wave * 16 + lane15;
            float al_inv = arow[qrow] * mrow[qrow];
            float ptinv = lrow[qrow];
            size_t base = ((size_t)(T0 + qrow) * NHEAD + h) * 64 + col;
            attout[base] = oacc[ms][r] * al_inv + ptinv * Vtail[base];
        }
}

extern "C" void kernel_launch(void* const* d_in, const int* in_sizes, int n_in,
                              void* d_out, int out_size, void* d_ws, size_t ws_size,
                              hipStream_t stream)
{
    const float* x   = (const float*)d_in[0];
    const float* Wq  = (const float*)d_in[1];
    const float* Wk  = (const float*)d_in[2];
    const float* Wv  = (const float*)d_in[3];
    const float* Wks = (const float*)d_in[4];
    const float* bks = (const float*)d_in[5];
    const float* Wvs = (const float*)d_in[6];
    const float* bvs = (const float*)d_in[7];
    const float* Wc  = (const float*)d_in[8];
    const float* bc  = (const float*)d_in[9];
    float* out = (float*)d_out;

    float* ws = (float*)d_ws;
    const size_t TC = (size_t)TLEN * CDIM;
    float* q      = ws;
    float* k      = q + TC;
    float* v      = k + TC;
    float* kkv    = v + TC;
    float* vvv    = kkv + TC;
    float* Kt     = vvv + TC;
    float* Vt     = Kt + TC;
    float* Kset   = Vt + TC;
    float* Vset   = Kset + (size_t)NSETS * CDIM;
    float* attout = Vset + (size_t)NSETS * CDIM;
    // Aliases into attout (written only by attn_mfma, after all alias readers):
    _Float16* WblobMap = (_Float16*)attout;                  // 262144 floats
    _Float16* blobQKV  = (_Float16*)(attout + 262144);       // 3 x 294912 floats (Q,K,V contiguous)
    float* scrK = attout + 1146880;
    float* scrV = scrK + 12 * 16 * 64;
    _Float16* blobC = (_Float16*)k;   // k dead after map_f16

    prep_w768x3<<<3 * 2304, 256, 0, stream>>>(Wq, Wk, Wv, blobQKV);
    prep_w<<<(4096 * 128) / 256, 256, 0, stream>>>(Wks, Wvs, WblobMap);

    gemm_qkv<<<dim3(36, 64), 256, 0, stream>>>(x, blobQKV, q);

    map_f16<<<(TLEN * NHEAD) / 32, 256, 0, stream>>>(k, v, WblobMap, kkv, vvv);

    prep_w768<<<2304, 256, 0, stream>>>(Wc, blobC);

    set_lower<<<16 * NHEAD, 256, 0, stream>>>(kkv, vvv, bks, bvs, Kset, Vset, scrK, scrV, Kt, Vt);
    set_upper<<<NHEAD, 256, 0, stream>>>(scrK, scrV, bks, bvs, Kset, Vset);

    attn_mfma<<<(TLEN / 32) * NHEAD, 256, 0, stream>>>(q, Kset, Vset, Kt, Vt, attout);

    gemm_mfma<0, 1><<<dim3(12, 64), 256, 0, stream>>>(attout, blobC, bc, out, TLEN, CDIM, CDIM);
}